// Round 2
// baseline (699.496 us; speedup 1.0000x reference)
//
#include <hip/hip_runtime.h>
#include <hip/hip_bf16.h>
#include <stdint.h>

#define L_SEQ 8192
#define S_SEQ 512
#define DIM   2048
#define CTX   4096
#define NH    16
#define HD    128

typedef __bf16 bf16_t;
typedef bf16_t bf16x8 __attribute__((ext_vector_type(8)));
typedef float  f32x4_t __attribute__((ext_vector_type(4)));

__device__ __forceinline__ ushort f2b(float f) {
  union { float f; uint32_t u; } v; v.f = f;
  uint32_t u = v.u;
  uint32_t r = (u + 0x7fffu + ((u >> 16) & 1u)) >> 16;
  return (ushort)r;
}
__device__ __forceinline__ uint32_t pk2(float a, float b) {
  return (uint32_t)f2b(a) | ((uint32_t)f2b(b) << 16);
}
__device__ __forceinline__ float b2f(ushort u) {
  union { uint32_t u; float f; } v; v.u = ((uint32_t)u) << 16;
  return v.f;
}

// ---------------- elementwise cast fp32 -> bf16 (8 elems/thread) ----------------
__global__ __launch_bounds__(256) void k_cast(const float* __restrict__ in,
                                              ushort* __restrict__ out) {
  const size_t i = ((size_t)blockIdx.x * 256 + threadIdx.x) * 8;
  float4 a = *(const float4*)(in + i);
  float4 b = *(const float4*)(in + i + 4);
  uint4 r;
  r.x = pk2(a.x, a.y); r.y = pk2(a.z, a.w);
  r.z = pk2(b.x, b.y); r.w = pk2(b.z, b.w);
  *(uint4*)(out + i) = r;
}

// ---------------- transpose + cast fp32 [K][N] -> bf16 [N][K] ----------------
__global__ __launch_bounds__(256) void k_tcast(const float* __restrict__ src,
                                               ushort* __restrict__ dst, int K, int N) {
  __shared__ float t[32][33];
  int tx = threadIdx.x, ty = threadIdx.y;
  int n0 = blockIdx.x * 32, k0 = blockIdx.y * 32;
#pragma unroll
  for (int i = 0; i < 4; i++)
    t[ty + 8 * i][tx] = src[(size_t)(k0 + ty + 8 * i) * N + n0 + tx];
  __syncthreads();
#pragma unroll
  for (int i = 0; i < 4; i++)
    dst[(size_t)(n0 + ty + 8 * i) * K + k0 + tx] = f2b(t[tx][ty + 8 * i]);
}

// ---------------- RMSNorm row kernel: bf16 [rows][2048] -> bf16, fused extra scale ----
__global__ __launch_bounds__(256) void k_rmsnorm(const ushort* __restrict__ in,
                                                 ushort* __restrict__ out,
                                                 const float* __restrict__ g, float scale) {
  const int row = blockIdx.x, tid = threadIdx.x;
  uint4 v = *(const uint4*)(in + (size_t)row * DIM + tid * 8);
  const uint32_t* vu = (const uint32_t*)&v;
  float f[8];
#pragma unroll
  for (int i = 0; i < 4; i++) {
    f[2 * i]     = b2f((ushort)(vu[i] & 0xffffu));
    f[2 * i + 1] = b2f((ushort)(vu[i] >> 16));
  }
  float s = 0.f;
#pragma unroll
  for (int i = 0; i < 8; i++) s += f[i] * f[i];
#pragma unroll
  for (int off = 32; off; off >>= 1) s += __shfl_down(s, off);
  __shared__ float wsum[4];
  __shared__ float rtot;
  if ((tid & 63) == 0) wsum[tid >> 6] = s;
  __syncthreads();
  if (tid == 0)
    rtot = rsqrtf((wsum[0] + wsum[1] + wsum[2] + wsum[3]) * (1.0f / DIM) + 1e-6f);
  __syncthreads();
  const float rms = rtot * scale;
  const float* gp = g + tid * 8;
  float4 g0 = *(const float4*)gp, g1 = *(const float4*)(gp + 4);
  ushort r[8];
  r[0] = f2b(f[0] * rms * g0.x); r[1] = f2b(f[1] * rms * g0.y);
  r[2] = f2b(f[2] * rms * g0.z); r[3] = f2b(f[3] * rms * g0.w);
  r[4] = f2b(f[4] * rms * g1.x); r[5] = f2b(f[5] * rms * g1.y);
  r[6] = f2b(f[6] * rms * g1.z); r[7] = f2b(f[7] * rms * g1.w);
  *(uint4*)(out + (size_t)row * DIM + tid * 8) = *(uint4*)r;
}

// ---------------- GEMM (m97 structure): C[M,N] = A[M,K] @ Bt[N,K]^T + bias ---------
// A bf16, Bt bf16 [N][K]. global_load_lds width-16 staging, linear LDS, 2 barriers/K.
// OUT_MODE 0: fp32 [M,N].  1: bf16 [M,N].  2: bf16 transposed [N,M] (V^T).
template <int OUT_MODE>
__global__ __launch_bounds__(256) void k_gemm_bt(const ushort* __restrict__ A,
                                                 const ushort* __restrict__ Bt,
                                                 const float* __restrict__ bias,
                                                 void* __restrict__ outp,
                                                 int M, int N, int K) {
  __shared__ __align__(16) ushort As[128 * 32];  // linear: required by global_load_lds
  __shared__ __align__(16) ushort Bs[128 * 32];
  const int tid = threadIdx.x;
  const int l = tid & 63, wid = tid >> 6;
  const int wr = wid >> 1, wc = wid & 1;
  const int lr = l & 15, lq = l >> 4;
  const int m0 = blockIdx.y * 128, n0 = blockIdx.x * 128;

  f32x4_t acc[4][4];
#pragma unroll
  for (int i = 0; i < 4; i++)
#pragma unroll
    for (int j = 0; j < 4; j++) acc[i][j] = f32x4_t{0.f, 0.f, 0.f, 0.f};

  // staging: tile = 8KB = 8 segments of 1KB; wave w stages segs {w, w+4}.
  // hardware writes lds_base + lane*16; lane i -> row seg*16 + i/4, col (i&3)*8.
  const int srow = l >> 2;
  const int scol = (l & 3) * 8;
  const ushort* ga0 = A  + (size_t)(m0 + wid * 16 + srow) * K + scol;
  const ushort* ga1 = A  + (size_t)(m0 + (4 + wid) * 16 + srow) * K + scol;
  const ushort* gb0 = Bt + (size_t)(n0 + wid * 16 + srow) * K + scol;
  const ushort* gb1 = Bt + (size_t)(n0 + (4 + wid) * 16 + srow) * K + scol;
  ushort* la0 = &As[wid * 512];
  ushort* la1 = &As[(4 + wid) * 512];
  ushort* lb0 = &Bs[wid * 512];
  ushort* lb1 = &Bs[(4 + wid) * 512];

  const int NT = K >> 5;
  for (int kt = 0; kt < NT; kt++) {
    __syncthreads();  // prior tile's ds_reads done before overwrite
    const int ko = kt * 32;
    __builtin_amdgcn_global_load_lds((const __attribute__((address_space(1))) void*)(ga0 + ko),
                                     (__attribute__((address_space(3))) void*)la0, 16, 0, 0);
    __builtin_amdgcn_global_load_lds((const __attribute__((address_space(1))) void*)(ga1 + ko),
                                     (__attribute__((address_space(3))) void*)la1, 16, 0, 0);
    __builtin_amdgcn_global_load_lds((const __attribute__((address_space(1))) void*)(gb0 + ko),
                                     (__attribute__((address_space(3))) void*)lb0, 16, 0, 0);
    __builtin_amdgcn_global_load_lds((const __attribute__((address_space(1))) void*)(gb1 + ko),
                                     (__attribute__((address_space(3))) void*)lb1, 16, 0, 0);
    __syncthreads();  // drains vmcnt(0): tile resident

    bf16x8 af[4], bfr[4];
#pragma unroll
    for (int mi = 0; mi < 4; mi++)
      af[mi] = *(const bf16x8*)(&As[(wr * 64 + mi * 16 + lr) * 32 + lq * 8]);
#pragma unroll
    for (int ni = 0; ni < 4; ni++)
      bfr[ni] = *(const bf16x8*)(&Bs[(wc * 64 + ni * 16 + lr) * 32 + lq * 8]);
#pragma unroll
    for (int mi = 0; mi < 4; mi++)
#pragma unroll
      for (int ni = 0; ni < 4; ni++)
        acc[mi][ni] = __builtin_amdgcn_mfma_f32_16x16x32_bf16(af[mi], bfr[ni], acc[mi][ni], 0, 0, 0);
  }

#pragma unroll
  for (int mi = 0; mi < 4; mi++) {
#pragma unroll
    for (int ni = 0; ni < 4; ni++) {
      const int col = n0 + wc * 64 + ni * 16 + lr;
      const float bv = bias[col];
#pragma unroll
      for (int r = 0; r < 4; r++) {
        const int row = m0 + wr * 64 + mi * 16 + lq * 4 + r;
        const float v = acc[mi][ni][r] + bv;
        if constexpr (OUT_MODE == 0)
          ((float*)outp)[(size_t)row * N + col] = v;
        else if constexpr (OUT_MODE == 1)
          ((ushort*)outp)[(size_t)row * N + col] = f2b(v);
        else
          ((ushort*)outp)[(size_t)col * M + row] = f2b(v);  // transposed bf16 (V^T)
      }
    }
  }
}

// ---------------- Flash attention: 4 independent waves x 16 q-rows ----------------
// K/V are L2-resident (128KB/head each): no LDS staging, no block barriers.
__global__ __launch_bounds__(256) void k_attn(const ushort* __restrict__ Qb,
                                              const ushort* __restrict__ Kb,
                                              const ushort* __restrict__ Vt,
                                              ushort* __restrict__ Ob) {
  __shared__ __align__(16) ushort Ps[4][16 * 72]; // per-wave P tile [16][64], stride 72
  const int tid = threadIdx.x;
  const int l = tid & 63, wid = tid >> 6;
  const int lr = l & 15, lq = l >> 4;
  const int h = blockIdx.y;
  const int q0 = blockIdx.x * 64 + wid * 16;

  bf16x8 aq[4];
  {
    const ushort* qp = Qb + (size_t)(q0 + lr) * DIM + h * HD;
#pragma unroll
    for (int kk = 0; kk < 4; kk++) aq[kk] = *(const bf16x8*)(qp + kk * 32 + lq * 8);
  }
  f32x4_t o[8];
#pragma unroll
  for (int i = 0; i < 8; i++) o[i] = f32x4_t{0.f, 0.f, 0.f, 0.f};
  float mrow[4] = {-1e30f, -1e30f, -1e30f, -1e30f};
  float lrow[4] = {0.f, 0.f, 0.f, 0.f};

  // per-lane fragment base pointers
  const ushort* kbase = Kb + (size_t)lr * DIM + h * HD + lq * 8;       // + (kvb*64+t*16)*DIM + kk*32
  const ushort* vbase = Vt + (size_t)(h * HD + lr) * S_SEQ + lq * 8;   // + dt*16*S_SEQ + kvb*64 + kq*32

  for (int kvb = 0; kvb < S_SEQ / 64; kvb++) {
    // scores: S = Q @ K^T (scale pre-folded into Q); K frags straight from L2
    f32x4_t s[4];
#pragma unroll
    for (int t = 0; t < 4; t++) {
      s[t] = f32x4_t{0.f, 0.f, 0.f, 0.f};
      const ushort* kp = kbase + (size_t)(kvb * 64 + t * 16) * DIM;
#pragma unroll
      for (int kk = 0; kk < 4; kk++) {
        bf16x8 bk = *(const bf16x8*)(kp + kk * 32);
        s[t] = __builtin_amdgcn_mfma_f32_16x16x32_bf16(aq[kk], bk, s[t], 0, 0, 0);
      }
    }
    // online softmax (row r of lane = q-row lq*4+r; 16 lanes share a row)
    float corr[4];
#pragma unroll
    for (int r = 0; r < 4; r++) {
      float rm = fmaxf(fmaxf(s[0][r], s[1][r]), fmaxf(s[2][r], s[3][r]));
#pragma unroll
      for (int mk = 1; mk < 16; mk <<= 1) rm = fmaxf(rm, __shfl_xor(rm, mk));
      const float mn = fmaxf(mrow[r], rm);
      corr[r] = __expf(mrow[r] - mn);
      mrow[r] = mn;
      float ps = 0.f;
#pragma unroll
      for (int t = 0; t < 4; t++) {
        const float p = __expf(s[t][r] - mn);
        s[t][r] = p; ps += p;
      }
#pragma unroll
      for (int mk = 1; mk < 16; mk <<= 1) ps += __shfl_xor(ps, mk);
      lrow[r] = lrow[r] * corr[r] + ps;
    }
    // P -> LDS (bf16), same-wave roundtrip re-layouts C-frag -> A-frag
    ushort* pw = &Ps[wid][0];
#pragma unroll
    for (int r = 0; r < 4; r++) {
      const int row = lq * 4 + r;
#pragma unroll
      for (int t = 0; t < 4; t++) pw[row * 72 + t * 16 + lr] = f2b(s[t][r]);
    }
    // rescale O
#pragma unroll
    for (int dt = 0; dt < 8; dt++)
#pragma unroll
      for (int r = 0; r < 4; r++) o[dt][r] *= corr[r];
    // PV: V^T frags straight from L2
#pragma unroll
    for (int kq = 0; kq < 2; kq++) {
      bf16x8 pa = *(const bf16x8*)(&pw[lr * 72 + kq * 32 + lq * 8]);
      const ushort* vp = vbase + kvb * 64 + kq * 32;
#pragma unroll
      for (int dt = 0; dt < 8; dt++) {
        bf16x8 vb = *(const bf16x8*)(vp + (size_t)(dt * 16) * S_SEQ);
        o[dt] = __builtin_amdgcn_mfma_f32_16x16x32_bf16(pa, vb, o[dt], 0, 0, 0);
      }
    }
  }
  // epilogue: normalize + store bf16 [L][H*D]
#pragma unroll
  for (int r = 0; r < 4; r++) {
    const float inv = 1.0f / lrow[r];
    const int row = q0 + lq * 4 + r;
#pragma unroll
    for (int dt = 0; dt < 8; dt++)
      Ob[(size_t)row * DIM + h * HD + dt * 16 + lr] = f2b(o[dt][r] * inv);
  }
}

extern "C" void kernel_launch(void* const* d_in, const int* in_sizes, int n_in,
                              void* d_out, int out_size, void* d_ws, size_t ws_size,
                              hipStream_t stream) {
  const float* x   = (const float*)d_in[0];
  const float* ctx = (const float*)d_in[1];
  const float* Wq  = (const float*)d_in[2];
  const float* bq  = (const float*)d_in[3];
  const float* Wk  = (const float*)d_in[4];
  const float* bk  = (const float*)d_in[5];
  const float* Wv  = (const float*)d_in[6];
  const float* bv  = (const float*)d_in[7];
  const float* Wo  = (const float*)d_in[8];
  const float* bo  = (const float*)d_in[9];
  const float* gq  = (const float*)d_in[10];
  const float* gk  = (const float*)d_in[11];

  char* ws = (char*)d_ws;
  ushort* wqt   = (ushort*)(ws);                 // [2048][2048] bf16   8.39MB
  ushort* wkt   = (ushort*)(ws + 8388608);       // [2048][4096] bf16  16.78MB
  ushort* wvt   = (ushort*)(ws + 25165824);      // [2048][4096] bf16  16.78MB
  ushort* wot   = (ushort*)(ws + 41943040);      // [2048][2048] bf16   8.39MB
  ushort* qb    = (ushort*)(ws + 50331648);      // [8192][2048] bf16  33.55MB (normalized Q)
  ushort* kb    = (ushort*)(ws + 83886080);      // [512][2048]  bf16   2.10MB (normalized K)
  ushort* vt    = (ushort*)(ws + 85983232);      // [2048][512]  bf16   2.10MB (V^T per-head)
  ushort* xb    = (ushort*)(ws + 88080384);      // [8192][2048] bf16  33.55MB (x cast)
  ushort* ctxb  = (ushort*)(ws + 88080384);      // [512][4096]  bf16   4.19MB (reuses xb after Qproj)
  ushort* qraw  = (ushort*)(ws + 121634816);     // [8192][2048] bf16  33.55MB (pre-norm Q)
  ushort* kraw  = (ushort*)(ws + 121634816);     // [512][2048]  bf16   2.10MB (reuses qraw)
  ushort* attnb = (ushort*)(ws + 121634816);     // [8192][2048] bf16  33.55MB (reuses after K norm)

  // input casts + weight transposes
  k_cast<<<L_SEQ * DIM / 8 / 256, 256, 0, stream>>>(x, xb);
  k_tcast<<<dim3(DIM / 32, DIM / 32), dim3(32, 8), 0, stream>>>(Wq, wqt, DIM, DIM);
  k_tcast<<<dim3(DIM / 32, CTX / 32), dim3(32, 8), 0, stream>>>(Wk, wkt, CTX, DIM);
  k_tcast<<<dim3(DIM / 32, CTX / 32), dim3(32, 8), 0, stream>>>(Wv, wvt, CTX, DIM);
  k_tcast<<<dim3(DIM / 32, DIM / 32), dim3(32, 8), 0, stream>>>(Wo, wot, DIM, DIM);

  // Q path: q_raw = x@Wq + bq (bf16) -> rmsnorm*g_q with softmax scale folded
  k_gemm_bt<1><<<dim3(DIM / 128, L_SEQ / 128), 256, 0, stream>>>(xb, wqt, bq, qraw, L_SEQ, DIM, DIM);
  k_cast<<<S_SEQ * CTX / 8 / 256, 256, 0, stream>>>(ctx, ctxb);  // after Qproj: reuses xb region
  k_rmsnorm<<<L_SEQ, 256, 0, stream>>>(qraw, qb, gq, 0.08838834764831843f);
  // K path
  k_gemm_bt<1><<<dim3(DIM / 128, S_SEQ / 128), 256, 0, stream>>>(ctxb, wkt, bk, kraw, S_SEQ, DIM, CTX);
  k_rmsnorm<<<S_SEQ, 256, 0, stream>>>(kraw, kb, gk, 1.0f);
  // V^T = (ctx@Wv + bv)^T
  k_gemm_bt<2><<<dim3(DIM / 128, S_SEQ / 128), 256, 0, stream>>>(ctxb, wvt, bv, vt, S_SEQ, DIM, CTX);
  // attention
  k_attn<<<dim3(L_SEQ / 64, NH), 256, 0, stream>>>(qb, kb, vt, attnb);
  // out = attn @ Wo + bo (fp32)
  k_gemm_bt<0><<<dim3(DIM / 128, L_SEQ / 128), 256, 0, stream>>>(attnb, wot, bo, d_out, L_SEQ, DIM, DIM);
}

// Round 3
// 501.371 us; speedup vs baseline: 1.3952x; 1.3952x over previous
//
#include <hip/hip_runtime.h>
#include <hip/hip_bf16.h>
#include <stdint.h>

#define L_SEQ 8192
#define S_SEQ 512
#define DIM   2048
#define CTX   4096
#define NH    16
#define HD    128

typedef __bf16 bf16_t;
typedef bf16_t bf16x8 __attribute__((ext_vector_type(8)));
typedef float  f32x4_t __attribute__((ext_vector_type(4)));

__device__ __forceinline__ ushort f2b(float f) {
  union { float f; uint32_t u; } v; v.f = f;
  uint32_t u = v.u;
  uint32_t r = (u + 0x7fffu + ((u >> 16) & 1u)) >> 16;
  return (ushort)r;
}
__device__ __forceinline__ uint32_t pk2(float a, float b) {
  return (uint32_t)f2b(a) | ((uint32_t)f2b(b) << 16);
}
__device__ __forceinline__ float b2f(ushort u) {
  union { uint32_t u; float f; } v; v.u = ((uint32_t)u) << 16;
  return v.f;
}

// ---------------- elementwise cast fp32 -> bf16 (8 elems/thread) ----------------
__global__ __launch_bounds__(256) void k_cast(const float* __restrict__ in,
                                              ushort* __restrict__ out) {
  const size_t i = ((size_t)blockIdx.x * 256 + threadIdx.x) * 8;
  float4 a = *(const float4*)(in + i);
  float4 b = *(const float4*)(in + i + 4);
  uint4 r;
  r.x = pk2(a.x, a.y); r.y = pk2(a.z, a.w);
  r.z = pk2(b.x, b.y); r.w = pk2(b.z, b.w);
  *(uint4*)(out + i) = r;
}

// ---------------- transpose + cast fp32 [K][N] -> bf16 [N][K] ----------------
__global__ __launch_bounds__(256) void k_tcast(const float* __restrict__ src,
                                               ushort* __restrict__ dst, int K, int N) {
  __shared__ float t[32][33];
  int tx = threadIdx.x, ty = threadIdx.y;
  int n0 = blockIdx.x * 32, k0 = blockIdx.y * 32;
#pragma unroll
  for (int i = 0; i < 4; i++)
    t[ty + 8 * i][tx] = src[(size_t)(k0 + ty + 8 * i) * N + n0 + tx];
  __syncthreads();
#pragma unroll
  for (int i = 0; i < 4; i++)
    dst[(size_t)(n0 + ty + 8 * i) * K + k0 + tx] = f2b(t[tx][ty + 8 * i]);
}

// ---------------- RMSNorm row kernel: bf16 [rows][2048] -> bf16, fused extra scale ----
__global__ __launch_bounds__(256) void k_rmsnorm(const ushort* __restrict__ in,
                                                 ushort* __restrict__ out,
                                                 const float* __restrict__ g, float scale) {
  const int row = blockIdx.x, tid = threadIdx.x;
  uint4 v = *(const uint4*)(in + (size_t)row * DIM + tid * 8);
  const uint32_t* vu = (const uint32_t*)&v;
  float f[8];
#pragma unroll
  for (int i = 0; i < 4; i++) {
    f[2 * i]     = b2f((ushort)(vu[i] & 0xffffu));
    f[2 * i + 1] = b2f((ushort)(vu[i] >> 16));
  }
  float s = 0.f;
#pragma unroll
  for (int i = 0; i < 8; i++) s += f[i] * f[i];
#pragma unroll
  for (int off = 32; off; off >>= 1) s += __shfl_down(s, off);
  __shared__ float wsum[4];
  __shared__ float rtot;
  if ((tid & 63) == 0) wsum[tid >> 6] = s;
  __syncthreads();
  if (tid == 0)
    rtot = rsqrtf((wsum[0] + wsum[1] + wsum[2] + wsum[3]) * (1.0f / DIM) + 1e-6f);
  __syncthreads();
  const float rms = rtot * scale;
  const float* gp = g + tid * 8;
  float4 g0 = *(const float4*)gp, g1 = *(const float4*)(gp + 4);
  ushort r[8];
  r[0] = f2b(f[0] * rms * g0.x); r[1] = f2b(f[1] * rms * g0.y);
  r[2] = f2b(f[2] * rms * g0.z); r[3] = f2b(f[3] * rms * g0.w);
  r[4] = f2b(f[4] * rms * g1.x); r[5] = f2b(f[5] * rms * g1.y);
  r[6] = f2b(f[6] * rms * g1.z); r[7] = f2b(f[7] * rms * g1.w);
  *(uint4*)(out + (size_t)row * DIM + tid * 8) = *(uint4*)r;
}

// ---------------- GEMM (m97 structure + XCD swizzle): C = A @ Bt^T + bias ---------
// A bf16 [M][K], Bt bf16 [N][K]. global_load_lds width-16, linear LDS, 2 barriers/K.
// OUT_MODE 0: fp32 [M,N].  1: bf16 [M,N].
// OUT_MODE 3: split KV epilogue — cols<DIM -> bf16 [M,DIM] (outp,bias);
//             cols>=DIM -> bf16 transposed [N-DIM rows][M] (outp2,bias2).
template <int OUT_MODE>
__global__ __launch_bounds__(256) void k_gemm_bt(const ushort* __restrict__ A,
                                                 const ushort* __restrict__ Bt,
                                                 const float* __restrict__ bias,
                                                 const float* __restrict__ bias2,
                                                 void* __restrict__ outp,
                                                 void* __restrict__ outp2,
                                                 int M, int N, int K) {
  __shared__ __align__(16) ushort As[128 * 32];  // linear: required by global_load_lds
  __shared__ __align__(16) ushort Bs[128 * 32];
  const int tid = threadIdx.x;
  const int l = tid & 63, wid = tid >> 6;
  const int wr = wid >> 1, wc = wid & 1;
  const int lr = l & 15, lq = l >> 4;

  // XCD-aware bijective swizzle (nwg % 8 == 0 for all our grids)
  const int nwg = gridDim.x * gridDim.y;
  const int bid = blockIdx.y * gridDim.x + blockIdx.x;
  const int swz = (bid & 7) * (nwg >> 3) + (bid >> 3);
  const int m0 = (swz / gridDim.x) * 128, n0 = (swz % gridDim.x) * 128;

  f32x4_t acc[4][4];
#pragma unroll
  for (int i = 0; i < 4; i++)
#pragma unroll
    for (int j = 0; j < 4; j++) acc[i][j] = f32x4_t{0.f, 0.f, 0.f, 0.f};

  // staging: tile = 8KB = 8 segments of 1KB; wave w stages segs {w, w+4}.
  const int srow = l >> 2;
  const int scol = (l & 3) * 8;
  const ushort* ga0 = A  + (size_t)(m0 + wid * 16 + srow) * K + scol;
  const ushort* ga1 = A  + (size_t)(m0 + (4 + wid) * 16 + srow) * K + scol;
  const ushort* gb0 = Bt + (size_t)(n0 + wid * 16 + srow) * K + scol;
  const ushort* gb1 = Bt + (size_t)(n0 + (4 + wid) * 16 + srow) * K + scol;
  ushort* la0 = &As[wid * 512];
  ushort* la1 = &As[(4 + wid) * 512];
  ushort* lb0 = &Bs[wid * 512];
  ushort* lb1 = &Bs[(4 + wid) * 512];

  const int NT = K >> 5;
  for (int kt = 0; kt < NT; kt++) {
    __syncthreads();
    const int ko = kt * 32;
    __builtin_amdgcn_global_load_lds((const __attribute__((address_space(1))) void*)(ga0 + ko),
                                     (__attribute__((address_space(3))) void*)la0, 16, 0, 0);
    __builtin_amdgcn_global_load_lds((const __attribute__((address_space(1))) void*)(ga1 + ko),
                                     (__attribute__((address_space(3))) void*)la1, 16, 0, 0);
    __builtin_amdgcn_global_load_lds((const __attribute__((address_space(1))) void*)(gb0 + ko),
                                     (__attribute__((address_space(3))) void*)lb0, 16, 0, 0);
    __builtin_amdgcn_global_load_lds((const __attribute__((address_space(1))) void*)(gb1 + ko),
                                     (__attribute__((address_space(3))) void*)lb1, 16, 0, 0);
    __syncthreads();

    bf16x8 af[4], bfr[4];
#pragma unroll
    for (int mi = 0; mi < 4; mi++)
      af[mi] = *(const bf16x8*)(&As[(wr * 64 + mi * 16 + lr) * 32 + lq * 8]);
#pragma unroll
    for (int ni = 0; ni < 4; ni++)
      bfr[ni] = *(const bf16x8*)(&Bs[(wc * 64 + ni * 16 + lr) * 32 + lq * 8]);
#pragma unroll
    for (int mi = 0; mi < 4; mi++)
#pragma unroll
      for (int ni = 0; ni < 4; ni++)
        acc[mi][ni] = __builtin_amdgcn_mfma_f32_16x16x32_bf16(af[mi], bfr[ni], acc[mi][ni], 0, 0, 0);
  }

#pragma unroll
  for (int mi = 0; mi < 4; mi++) {
#pragma unroll
    for (int ni = 0; ni < 4; ni++) {
      const int col = n0 + wc * 64 + ni * 16 + lr;
      float bv;
      if constexpr (OUT_MODE == 3) bv = (col < DIM) ? bias[col] : bias2[col - DIM];
      else bv = bias[col];
#pragma unroll
      for (int r = 0; r < 4; r++) {
        const int row = m0 + wr * 64 + mi * 16 + lq * 4 + r;
        const float v = acc[mi][ni][r] + bv;
        if constexpr (OUT_MODE == 0)
          ((float*)outp)[(size_t)row * N + col] = v;
        else if constexpr (OUT_MODE == 1)
          ((ushort*)outp)[(size_t)row * N + col] = f2b(v);
        else {
          if (col < DIM) ((ushort*)outp)[(size_t)row * DIM + col] = f2b(v);
          else ((ushort*)outp2)[(size_t)(col - DIM) * M + row] = f2b(v);  // V^T
        }
      }
    }
  }
}

// ---------------- Flash attention: 4 waves x 32 q-rows, KV block 64, LDS staged ----
__global__ __launch_bounds__(256) void k_attn(const ushort* __restrict__ Qb,
                                              const ushort* __restrict__ Kb,
                                              const ushort* __restrict__ Vt,
                                              ushort* __restrict__ Ob) {
  __shared__ __align__(16) ushort Ks[64 * 136];   // [kv 64][d 128], stride 136
  __shared__ __align__(16) ushort Vs[128 * 72];   // [d 128][s 64], stride 72
  __shared__ __align__(16) ushort Ps[4][32 * 72]; // per-wave P tile [32][64], stride 72
  const int tid = threadIdx.x;
  const int l = tid & 63, wid = tid >> 6;
  const int lr = l & 15, lq = l >> 4;

  // XCD swizzle: heads grouped per XCD (K/V stay resident in one L2)
  const int bid = blockIdx.x;                  // grid = 1024
  const int swz = (bid & 7) * 128 + (bid >> 3);
  const int h = swz >> 6;                      // 0..15
  const int q0 = (swz & 63) * 128 + wid * 32;  // 32 q-rows per wave

  bf16x8 aq[2][4];
#pragma unroll
  for (int m = 0; m < 2; m++) {
    const ushort* qp = Qb + (size_t)(q0 + m * 16 + lr) * DIM + h * HD;
#pragma unroll
    for (int kk = 0; kk < 4; kk++) aq[m][kk] = *(const bf16x8*)(qp + kk * 32 + lq * 8);
  }
  f32x4_t o[2][8];
#pragma unroll
  for (int m = 0; m < 2; m++)
#pragma unroll
    for (int i = 0; i < 8; i++) o[m][i] = f32x4_t{0.f, 0.f, 0.f, 0.f};
  float mrow[2][4], lrow[2][4];
#pragma unroll
  for (int m = 0; m < 2; m++)
#pragma unroll
    for (int r = 0; r < 4; r++) { mrow[m][r] = -1e30f; lrow[m][r] = 0.f; }

  auto loadK = [&](int kvb, int i) -> uint4 {
    const int c = i * 256 + tid, row = c >> 4, u = c & 15;
    return *(const uint4*)(Kb + (size_t)(kvb * 64 + row) * DIM + h * HD + u * 8);
  };
  auto loadV = [&](int kvb, int i) -> uint4 {
    const int c = i * 256 + tid, d = c >> 3, u = c & 7;
    return *(const uint4*)(Vt + (size_t)(h * HD + d) * S_SEQ + kvb * 64 + u * 8);
  };
  uint4 rk[4], rv[4];
#pragma unroll
  for (int i = 0; i < 4; i++) { rk[i] = loadK(0, i); rv[i] = loadV(0, i); }

  for (int kvb = 0; kvb < S_SEQ / 64; kvb++) {
    __syncthreads();
#pragma unroll
    for (int i = 0; i < 4; i++) {
      const int c = i * 256 + tid;
      *(uint4*)(&Ks[(c >> 4) * 136 + (c & 15) * 8]) = rk[i];
      *(uint4*)(&Vs[(c >> 3) * 72 + (c & 7) * 8]) = rv[i];
    }
    if (kvb + 1 < S_SEQ / 64) {
#pragma unroll
      for (int i = 0; i < 4; i++) { rk[i] = loadK(kvb + 1, i); rv[i] = loadV(kvb + 1, i); }
    }
    __syncthreads();

    // scores: S = Q @ K^T (scale pre-folded into Q); K frags shared across m-tiles
    f32x4_t s[2][4];
#pragma unroll
    for (int m = 0; m < 2; m++)
#pragma unroll
      for (int t = 0; t < 4; t++) s[m][t] = f32x4_t{0.f, 0.f, 0.f, 0.f};
#pragma unroll
    for (int t = 0; t < 4; t++) {
      bf16x8 bk[4];
#pragma unroll
      for (int kk = 0; kk < 4; kk++)
        bk[kk] = *(const bf16x8*)(&Ks[(t * 16 + lr) * 136 + kk * 32 + lq * 8]);
#pragma unroll
      for (int m = 0; m < 2; m++)
#pragma unroll
        for (int kk = 0; kk < 4; kk++)
          s[m][t] = __builtin_amdgcn_mfma_f32_16x16x32_bf16(aq[m][kk], bk[kk], s[m][t], 0, 0, 0);
    }
    // online softmax (16 lanes share each q-row)
    float corr[2][4];
#pragma unroll
    for (int m = 0; m < 2; m++)
#pragma unroll
      for (int r = 0; r < 4; r++) {
        float rm = fmaxf(fmaxf(s[m][0][r], s[m][1][r]), fmaxf(s[m][2][r], s[m][3][r]));
#pragma unroll
        for (int mk = 1; mk < 16; mk <<= 1) rm = fmaxf(rm, __shfl_xor(rm, mk));
        const float mn = fmaxf(mrow[m][r], rm);
        corr[m][r] = __expf(mrow[m][r] - mn);
        mrow[m][r] = mn;
        float ps = 0.f;
#pragma unroll
        for (int t = 0; t < 4; t++) {
          const float p = __expf(s[m][t][r] - mn);
          s[m][t][r] = p; ps += p;
        }
#pragma unroll
        for (int mk = 1; mk < 16; mk <<= 1) ps += __shfl_xor(ps, mk);
        lrow[m][r] = lrow[m][r] * corr[m][r] + ps;
      }
    // P -> LDS (bf16): same-wave roundtrip re-layouts C-frag -> A-frag
    ushort* pw = &Ps[wid][0];
#pragma unroll
    for (int m = 0; m < 2; m++)
#pragma unroll
      for (int r = 0; r < 4; r++) {
        const int row = m * 16 + lq * 4 + r;
#pragma unroll
        for (int t = 0; t < 4; t++) pw[row * 72 + t * 16 + lr] = f2b(s[m][t][r]);
      }
    // rescale O
#pragma unroll
    for (int m = 0; m < 2; m++)
#pragma unroll
      for (int dt = 0; dt < 8; dt++)
#pragma unroll
        for (int r = 0; r < 4; r++) o[m][dt][r] *= corr[m][r];
    // PV: V frags shared across m-tiles
#pragma unroll
    for (int kq = 0; kq < 2; kq++) {
      bf16x8 pa[2];
#pragma unroll
      for (int m = 0; m < 2; m++)
        pa[m] = *(const bf16x8*)(&pw[(m * 16 + lr) * 72 + kq * 32 + lq * 8]);
#pragma unroll
      for (int dt = 0; dt < 8; dt++) {
        bf16x8 vb = *(const bf16x8*)(&Vs[(dt * 16 + lr) * 72 + kq * 32 + lq * 8]);
#pragma unroll
        for (int m = 0; m < 2; m++)
          o[m][dt] = __builtin_amdgcn_mfma_f32_16x16x32_bf16(pa[m], vb, o[m][dt], 0, 0, 0);
      }
    }
  }
  // epilogue: normalize + store bf16 [L][H*D]
#pragma unroll
  for (int m = 0; m < 2; m++)
#pragma unroll
    for (int r = 0; r < 4; r++) {
      const float inv = 1.0f / lrow[m][r];
      const int row = q0 + m * 16 + lq * 4 + r;
#pragma unroll
      for (int dt = 0; dt < 8; dt++)
        Ob[(size_t)row * DIM + h * HD + dt * 16 + lr] = f2b(o[m][dt][r] * inv);
    }
}

extern "C" void kernel_launch(void* const* d_in, const int* in_sizes, int n_in,
                              void* d_out, int out_size, void* d_ws, size_t ws_size,
                              hipStream_t stream) {
  const float* x   = (const float*)d_in[0];
  const float* ctx = (const float*)d_in[1];
  const float* Wq  = (const float*)d_in[2];
  const float* bq  = (const float*)d_in[3];
  const float* Wk  = (const float*)d_in[4];
  const float* bk  = (const float*)d_in[5];
  const float* Wv  = (const float*)d_in[6];
  const float* bv  = (const float*)d_in[7];
  const float* Wo  = (const float*)d_in[8];
  const float* bo  = (const float*)d_in[9];
  const float* gq  = (const float*)d_in[10];
  const float* gk  = (const float*)d_in[11];

  char* ws = (char*)d_ws;
  ushort* wqt   = (ushort*)(ws);                 // [2048][2048] bf16   8.39MB
  ushort* wkt   = (ushort*)(ws + 8388608);       // [2048][4096] bf16  16.78MB  } adjacent =>
  ushort* wvt   = (ushort*)(ws + 25165824);      // [2048][4096] bf16  16.78MB  } [4096][4096] KV
  ushort* wot   = (ushort*)(ws + 41943040);      // [2048][2048] bf16   8.39MB
  ushort* qb    = (ushort*)(ws + 50331648);      // [8192][2048] bf16  33.55MB (normalized Q)
  ushort* kb    = (ushort*)(ws + 83886080);      // [512][2048]  bf16   2.10MB (normalized K)
  ushort* vt    = (ushort*)(ws + 85983232);      // [2048][512]  bf16   2.10MB (V^T per-head)
  ushort* xb    = (ushort*)(ws + 88080384);      // [8192][2048] bf16  33.55MB (x cast)
  ushort* ctxb  = (ushort*)(ws + 88080384);      // [512][4096]  bf16   4.19MB (reuses xb)
  ushort* qraw  = (ushort*)(ws + 121634816);     // [8192][2048] bf16  33.55MB (pre-norm Q)
  ushort* kraw  = (ushort*)(ws + 121634816);     // [512][2048]  bf16   2.10MB (reuses qraw)
  ushort* attnb = (ushort*)(ws + 121634816);     // [8192][2048] bf16  33.55MB (reuses after K norm)

  // input casts + weight transposes
  k_cast<<<L_SEQ * DIM / 8 / 256, 256, 0, stream>>>(x, xb);
  k_tcast<<<dim3(DIM / 32, DIM / 32), dim3(32, 8), 0, stream>>>(Wq, wqt, DIM, DIM);
  k_tcast<<<dim3(DIM / 32, CTX / 32), dim3(32, 8), 0, stream>>>(Wk, wkt, CTX, DIM);
  k_tcast<<<dim3(DIM / 32, CTX / 32), dim3(32, 8), 0, stream>>>(Wv, wvt, CTX, DIM);
  k_tcast<<<dim3(DIM / 32, DIM / 32), dim3(32, 8), 0, stream>>>(Wo, wot, DIM, DIM);

  // Q path: q_raw = x@Wq + bq (bf16) -> rmsnorm*g_q with softmax scale folded
  k_gemm_bt<1><<<dim3(DIM / 128, L_SEQ / 128), 256, 0, stream>>>(xb, wqt, bq, nullptr, qraw, nullptr, L_SEQ, DIM, DIM);
  k_cast<<<S_SEQ * CTX / 8 / 256, 256, 0, stream>>>(ctx, ctxb);
  k_rmsnorm<<<L_SEQ, 256, 0, stream>>>(qraw, qb, gq, 0.08838834764831843f);
  // fused K+V projection: Bt = [Wk^T ; Wv^T] (adjacent in ws), N=4096
  k_gemm_bt<3><<<dim3(2 * DIM / 128, S_SEQ / 128), 256, 0, stream>>>(ctxb, wkt, bk, bv, kraw, vt, S_SEQ, 2 * DIM, CTX);
  k_rmsnorm<<<S_SEQ, 256, 0, stream>>>(kraw, kb, gk, 1.0f);
  // attention
  k_attn<<<L_SEQ / 128 * NH, 256, 0, stream>>>(qb, kb, vt, attnb);
  // out = attn @ Wo + bo (fp32)
  k_gemm_bt<0><<<dim3(DIM / 128, L_SEQ / 128), 256, 0, stream>>>(attnb, wot, bo, nullptr, d_out, nullptr, L_SEQ, DIM, DIM);
}

// Round 4
// 435.666 us; speedup vs baseline: 1.6056x; 1.1508x over previous
//
#include <hip/hip_runtime.h>
#include <hip/hip_bf16.h>
#include <stdint.h>

#define L_SEQ 8192
#define S_SEQ 512
#define DIM   2048
#define CTX   4096
#define NH    16
#define HD    128

typedef __bf16 bf16_t;
typedef bf16_t bf16x8 __attribute__((ext_vector_type(8)));
typedef float  f32x4_t __attribute__((ext_vector_type(4)));

__device__ __forceinline__ ushort f2b(float f) {
  union { float f; uint32_t u; } v; v.f = f;
  uint32_t u = v.u;
  uint32_t r = (u + 0x7fffu + ((u >> 16) & 1u)) >> 16;
  return (ushort)r;
}
__device__ __forceinline__ uint32_t pk2(float a, float b) {
  return (uint32_t)f2b(a) | ((uint32_t)f2b(b) << 16);
}
__device__ __forceinline__ float b2f(ushort u) {
  union { uint32_t u; float f; } v; v.u = ((uint32_t)u) << 16;
  return v.f;
}
__device__ __forceinline__ void gll16(const ushort* g, ushort* l) {
  __builtin_amdgcn_global_load_lds((const __attribute__((address_space(1))) void*)g,
                                   (__attribute__((address_space(3))) void*)l, 16, 0, 0);
}

// ---------------- elementwise cast fp32 -> bf16 (8 elems/thread) ----------------
__global__ __launch_bounds__(256) void k_cast(const float* __restrict__ in,
                                              ushort* __restrict__ out) {
  const size_t i = ((size_t)blockIdx.x * 256 + threadIdx.x) * 8;
  float4 a = *(const float4*)(in + i);
  float4 b = *(const float4*)(in + i + 4);
  uint4 r;
  r.x = pk2(a.x, a.y); r.y = pk2(a.z, a.w);
  r.z = pk2(b.x, b.y); r.w = pk2(b.z, b.w);
  *(uint4*)(out + i) = r;
}

// ---------------- transpose + cast fp32 [K][N] -> bf16 [N][K] ----------------
__global__ __launch_bounds__(256) void k_tcast(const float* __restrict__ src,
                                               ushort* __restrict__ dst, int K, int N) {
  __shared__ float t[32][33];
  int tx = threadIdx.x, ty = threadIdx.y;
  int n0 = blockIdx.x * 32, k0 = blockIdx.y * 32;
#pragma unroll
  for (int i = 0; i < 4; i++)
    t[ty + 8 * i][tx] = src[(size_t)(k0 + ty + 8 * i) * N + n0 + tx];
  __syncthreads();
#pragma unroll
  for (int i = 0; i < 4; i++)
    dst[(size_t)(n0 + ty + 8 * i) * K + k0 + tx] = f2b(t[tx][ty + 8 * i]);
}

// ---------------- RMSNorm row kernel: bf16 [rows][2048] -> bf16, fused extra scale ----
__global__ __launch_bounds__(256) void k_rmsnorm(const ushort* __restrict__ in,
                                                 ushort* __restrict__ out,
                                                 const float* __restrict__ g, float scale) {
  const int row = blockIdx.x, tid = threadIdx.x;
  uint4 v = *(const uint4*)(in + (size_t)row * DIM + tid * 8);
  const uint32_t* vu = (const uint32_t*)&v;
  float f[8];
#pragma unroll
  for (int i = 0; i < 4; i++) {
    f[2 * i]     = b2f((ushort)(vu[i] & 0xffffu));
    f[2 * i + 1] = b2f((ushort)(vu[i] >> 16));
  }
  float s = 0.f;
#pragma unroll
  for (int i = 0; i < 8; i++) s += f[i] * f[i];
#pragma unroll
  for (int off = 32; off; off >>= 1) s += __shfl_down(s, off);
  __shared__ float wsum[4];
  __shared__ float rtot;
  if ((tid & 63) == 0) wsum[tid >> 6] = s;
  __syncthreads();
  if (tid == 0)
    rtot = rsqrtf((wsum[0] + wsum[1] + wsum[2] + wsum[3]) * (1.0f / DIM) + 1e-6f);
  __syncthreads();
  const float rms = rtot * scale;
  const float* gp = g + tid * 8;
  float4 g0 = *(const float4*)gp, g1 = *(const float4*)(gp + 4);
  ushort r[8];
  r[0] = f2b(f[0] * rms * g0.x); r[1] = f2b(f[1] * rms * g0.y);
  r[2] = f2b(f[2] * rms * g0.z); r[3] = f2b(f[3] * rms * g0.w);
  r[4] = f2b(f[4] * rms * g1.x); r[5] = f2b(f[5] * rms * g1.y);
  r[6] = f2b(f[6] * rms * g1.z); r[7] = f2b(f[7] * rms * g1.w);
  *(uint4*)(out + (size_t)row * DIM + tid * 8) = *(uint4*)r;
}

// ======================= 256x256 8-wave 4-phase GEMM =======================
// C[M,N] = A[M,K] @ Bt[N,K]^T + bias. BK=64, 512 threads (2Mx4N waves).
// LDS 128KB: 2 dbuf x (A 256x64 + B 256x64) bf16. XOR chunk-swizzle (T2) via
// inverse-swizzled global_load_lds source + swizzled ds_read (rule 21).
// Counted vmcnt(2) once per K-tile (T4), raw s_barrier phases (T3), setprio (T5).
// OUT_MODE 0: fp32 [M,N].  1: bf16 [M,N].
template <int OUT_MODE>
__global__ __launch_bounds__(512, 2) void k_gemm256(const ushort* __restrict__ A,
                                                    const ushort* __restrict__ Bt,
                                                    const float* __restrict__ bias,
                                                    void* __restrict__ outp,
                                                    int M, int N, int K) {
  __shared__ __align__(16) ushort lds[65536];  // 128 KB: buf b at b*32768; B-mat at +16384
  const int tid = threadIdx.x;
  const int l = tid & 63, wid = tid >> 6;
  const int wm = wid >> 2, wn = wid & 3;
  const int lr = l & 15, lq = l >> 4;

  // XCD-aware bijective swizzle (nwg % 8 == 0)
  const int nwg = gridDim.x * gridDim.y;
  const int bid = blockIdx.y * gridDim.x + blockIdx.x;
  const int swz = (bid & 7) * (nwg >> 3) + (bid >> 3);
  const int m0 = (swz / gridDim.x) * 256, n0 = (swz % gridDim.x) * 256;

  f32x4_t acc[8][4];
#pragma unroll
  for (int i = 0; i < 8; i++)
#pragma unroll
    for (int j = 0; j < 4; j++) acc[i][j] = f32x4_t{0.f, 0.f, 0.f, 0.f};

  // ---- staging geometry (global source carries the inverse swizzle) ----
  const int srow = l >> 3;                         // row within 8-row wave slice
  const int schunk = ((l & 7) ^ (srow & 7)) * 8;   // inverse-swizzled 8-elem chunk
  // stage half h (128 rows) of matrix mat for K-tile `tile` into buffer `buf`
  auto stage = [&](int buf, int tile, int mat, int h) {
    const ushort* gp = mat ? Bt : A;
    const int rn0 = mat ? n0 : m0;
    const size_t r0 = (size_t)(rn0 + h * 128 + wid * 8 + srow);
    const ushort* g0 = gp + r0 * K + tile * 64 + schunk;
    ushort* l0 = &lds[buf * 32768 + mat * 16384 + (h * 128 + wid * 8) * 64];
    gll16(g0, l0);
    gll16(g0 + (size_t)64 * K, l0 + 64 * 64);
  };

  // ---- swizzled fragment reads ----
  auto rdA = [&](int buf, int mf, int ks) -> bf16x8 {
    const int R = wm * 128 + mf * 16 + lr;
    return *(const bf16x8*)(&lds[buf * 32768 + R * 64 + (((ks * 4 + lq) ^ (R & 7)) * 8)]);
  };
  auto rdB = [&](int buf, int nf, int ks) -> bf16x8 {
    const int R = wn * 64 + nf * 16 + lr;
    return *(const bf16x8*)(&lds[buf * 32768 + 16384 + R * 64 + (((ks * 4 + lq) ^ (R & 7)) * 8)]);
  };

  const int NT = K >> 6;
  // prologue: stage tile 0 into buf 0
  stage(0, 0, 0, 0); stage(0, 0, 0, 1); stage(0, 0, 1, 0); stage(0, 0, 1, 1);

  bf16x8 a[4][2], a2[4][2], b[2][2], b2[2][2];
  for (int kt = 0; kt < NT; kt++) {
    const int cur = kt & 1, nxt = cur ^ 1;
    const bool pf = (kt + 1 < NT);
    // ---- P0: stage A-h0(next) -> counted vmcnt -> barrier -> read q0 -> MFMA ----
    if (pf) { stage(nxt, kt + 1, 0, 0); asm volatile("s_waitcnt vmcnt(2)" ::: "memory"); }
    else    { asm volatile("s_waitcnt vmcnt(0)" ::: "memory"); }
    __builtin_amdgcn_sched_barrier(0);
    __builtin_amdgcn_s_barrier();
    __builtin_amdgcn_sched_barrier(0);
#pragma unroll
    for (int mf = 0; mf < 4; mf++) { a[mf][0] = rdA(cur, mf, 0); a[mf][1] = rdA(cur, mf, 1); }
#pragma unroll
    for (int nf = 0; nf < 2; nf++) { b[nf][0] = rdB(cur, nf, 0); b[nf][1] = rdB(cur, nf, 1); }
    __builtin_amdgcn_s_setprio(1);
#pragma unroll
    for (int mf = 0; mf < 4; mf++)
#pragma unroll
      for (int nf = 0; nf < 2; nf++) {
        acc[mf][nf] = __builtin_amdgcn_mfma_f32_16x16x32_bf16(a[mf][0], b[nf][0], acc[mf][nf], 0, 0, 0);
        acc[mf][nf] = __builtin_amdgcn_mfma_f32_16x16x32_bf16(a[mf][1], b[nf][1], acc[mf][nf], 0, 0, 0);
      }
    __builtin_amdgcn_s_setprio(0);
    __builtin_amdgcn_sched_barrier(0);
    __builtin_amdgcn_s_barrier();
    __builtin_amdgcn_sched_barrier(0);
    // ---- P1: read q1 (A mf4-7) || stage A-h1 -> barrier -> MFMA ----
#pragma unroll
    for (int mf = 0; mf < 4; mf++) { a2[mf][0] = rdA(cur, mf + 4, 0); a2[mf][1] = rdA(cur, mf + 4, 1); }
    if (pf) stage(nxt, kt + 1, 0, 1);
    __builtin_amdgcn_sched_barrier(0);
    __builtin_amdgcn_s_barrier();
    __builtin_amdgcn_sched_barrier(0);
    __builtin_amdgcn_s_setprio(1);
#pragma unroll
    for (int mf = 0; mf < 4; mf++)
#pragma unroll
      for (int nf = 0; nf < 2; nf++) {
        acc[mf + 4][nf] = __builtin_amdgcn_mfma_f32_16x16x32_bf16(a2[mf][0], b[nf][0], acc[mf + 4][nf], 0, 0, 0);
        acc[mf + 4][nf] = __builtin_amdgcn_mfma_f32_16x16x32_bf16(a2[mf][1], b[nf][1], acc[mf + 4][nf], 0, 0, 0);
      }
    __builtin_amdgcn_s_setprio(0);
    __builtin_amdgcn_sched_barrier(0);
    __builtin_amdgcn_s_barrier();
    __builtin_amdgcn_sched_barrier(0);
    // ---- P2: read q2 (B nf2-3) || stage B-h0 -> barrier -> MFMA ----
#pragma unroll
    for (int nf = 0; nf < 2; nf++) { b2[nf][0] = rdB(cur, nf + 2, 0); b2[nf][1] = rdB(cur, nf + 2, 1); }
    if (pf) stage(nxt, kt + 1, 1, 0);
    __builtin_amdgcn_sched_barrier(0);
    __builtin_amdgcn_s_barrier();
    __builtin_amdgcn_sched_barrier(0);
    __builtin_amdgcn_s_setprio(1);
#pragma unroll
    for (int mf = 0; mf < 4; mf++)
#pragma unroll
      for (int nf = 0; nf < 2; nf++) {
        acc[mf + 4][nf + 2] = __builtin_amdgcn_mfma_f32_16x16x32_bf16(a2[mf][0], b2[nf][0], acc[mf + 4][nf + 2], 0, 0, 0);
        acc[mf + 4][nf + 2] = __builtin_amdgcn_mfma_f32_16x16x32_bf16(a2[mf][1], b2[nf][1], acc[mf + 4][nf + 2], 0, 0, 0);
      }
    __builtin_amdgcn_s_setprio(0);
    __builtin_amdgcn_sched_barrier(0);
    __builtin_amdgcn_s_barrier();
    __builtin_amdgcn_sched_barrier(0);
    // ---- P3: read q3 (A mf0-3 again) || stage B-h1 -> barrier -> MFMA ----
#pragma unroll
    for (int mf = 0; mf < 4; mf++) { a[mf][0] = rdA(cur, mf, 0); a[mf][1] = rdA(cur, mf, 1); }
    if (pf) stage(nxt, kt + 1, 1, 1);
    __builtin_amdgcn_sched_barrier(0);
    __builtin_amdgcn_s_barrier();
    __builtin_amdgcn_sched_barrier(0);
    __builtin_amdgcn_s_setprio(1);
#pragma unroll
    for (int mf = 0; mf < 4; mf++)
#pragma unroll
      for (int nf = 0; nf < 2; nf++) {
        acc[mf][nf + 2] = __builtin_amdgcn_mfma_f32_16x16x32_bf16(a[mf][0], b2[nf][0], acc[mf][nf + 2], 0, 0, 0);
        acc[mf][nf + 2] = __builtin_amdgcn_mfma_f32_16x16x32_bf16(a[mf][1], b2[nf][1], acc[mf][nf + 2], 0, 0, 0);
      }
    __builtin_amdgcn_s_setprio(0);
    __builtin_amdgcn_sched_barrier(0);
    __builtin_amdgcn_s_barrier();
    __builtin_amdgcn_sched_barrier(0);
  }

  // ---- epilogue ----
#pragma unroll
  for (int nf = 0; nf < 4; nf++) {
    const int col = n0 + wn * 64 + nf * 16 + lr;
    const float bv = bias[col];
#pragma unroll
    for (int mf = 0; mf < 8; mf++) {
#pragma unroll
      for (int r = 0; r < 4; r++) {
        const int row = m0 + wm * 128 + mf * 16 + lq * 4 + r;
        const float v = acc[mf][nf][r] + bv;
        if constexpr (OUT_MODE == 0)
          ((float*)outp)[(size_t)row * N + col] = v;
        else
          ((ushort*)outp)[(size_t)row * N + col] = f2b(v);
      }
    }
  }
}

// ---------------- 128x128 GEMM (m97 structure) for the small KV projection -------
// OUT_MODE 3: split KV epilogue — cols<DIM -> bf16 [M,DIM]; cols>=DIM -> bf16 [N-DIM][M]^T.
template <int OUT_MODE>
__global__ __launch_bounds__(256) void k_gemm_bt(const ushort* __restrict__ A,
                                                 const ushort* __restrict__ Bt,
                                                 const float* __restrict__ bias,
                                                 const float* __restrict__ bias2,
                                                 void* __restrict__ outp,
                                                 void* __restrict__ outp2,
                                                 int M, int N, int K) {
  __shared__ __align__(16) ushort As[128 * 32];
  __shared__ __align__(16) ushort Bs[128 * 32];
  const int tid = threadIdx.x;
  const int l = tid & 63, wid = tid >> 6;
  const int wr = wid >> 1, wc = wid & 1;
  const int lr = l & 15, lq = l >> 4;

  const int nwg = gridDim.x * gridDim.y;
  const int bid = blockIdx.y * gridDim.x + blockIdx.x;
  const int swz = (bid & 7) * (nwg >> 3) + (bid >> 3);
  const int m0 = (swz / gridDim.x) * 128, n0 = (swz % gridDim.x) * 128;

  f32x4_t acc[4][4];
#pragma unroll
  for (int i = 0; i < 4; i++)
#pragma unroll
    for (int j = 0; j < 4; j++) acc[i][j] = f32x4_t{0.f, 0.f, 0.f, 0.f};

  const int srow = l >> 2;
  const int scol = (l & 3) * 8;
  const ushort* ga0 = A  + (size_t)(m0 + wid * 16 + srow) * K + scol;
  const ushort* ga1 = A  + (size_t)(m0 + (4 + wid) * 16 + srow) * K + scol;
  const ushort* gb0 = Bt + (size_t)(n0 + wid * 16 + srow) * K + scol;
  const ushort* gb1 = Bt + (size_t)(n0 + (4 + wid) * 16 + srow) * K + scol;
  ushort* la0 = &As[wid * 512];
  ushort* la1 = &As[(4 + wid) * 512];
  ushort* lb0 = &Bs[wid * 512];
  ushort* lb1 = &Bs[(4 + wid) * 512];

  const int NT = K >> 5;
  for (int kt = 0; kt < NT; kt++) {
    __syncthreads();
    const int ko = kt * 32;
    gll16(ga0 + ko, la0);
    gll16(ga1 + ko, la1);
    gll16(gb0 + ko, lb0);
    gll16(gb1 + ko, lb1);
    __syncthreads();

    bf16x8 af[4], bfr[4];
#pragma unroll
    for (int mi = 0; mi < 4; mi++)
      af[mi] = *(const bf16x8*)(&As[(wr * 64 + mi * 16 + lr) * 32 + lq * 8]);
#pragma unroll
    for (int ni = 0; ni < 4; ni++)
      bfr[ni] = *(const bf16x8*)(&Bs[(wc * 64 + ni * 16 + lr) * 32 + lq * 8]);
#pragma unroll
    for (int mi = 0; mi < 4; mi++)
#pragma unroll
      for (int ni = 0; ni < 4; ni++)
        acc[mi][ni] = __builtin_amdgcn_mfma_f32_16x16x32_bf16(af[mi], bfr[ni], acc[mi][ni], 0, 0, 0);
  }

#pragma unroll
  for (int mi = 0; mi < 4; mi++) {
#pragma unroll
    for (int ni = 0; ni < 4; ni++) {
      const int col = n0 + wc * 64 + ni * 16 + lr;
      float bv;
      if constexpr (OUT_MODE == 3) bv = (col < DIM) ? bias[col] : bias2[col - DIM];
      else bv = bias[col];
#pragma unroll
      for (int r = 0; r < 4; r++) {
        const int row = m0 + wr * 64 + mi * 16 + lq * 4 + r;
        const float v = acc[mi][ni][r] + bv;
        if constexpr (OUT_MODE == 0)
          ((float*)outp)[(size_t)row * N + col] = v;
        else if constexpr (OUT_MODE == 1)
          ((ushort*)outp)[(size_t)row * N + col] = f2b(v);
        else {
          if (col < DIM) ((ushort*)outp)[(size_t)row * DIM + col] = f2b(v);
          else ((ushort*)outp2)[(size_t)(col - DIM) * M + row] = f2b(v);  // V^T
        }
      }
    }
  }
}

// ---------------- Flash attention: 4 waves x 32 q-rows, KV block 64, LDS staged ----
__global__ __launch_bounds__(256) void k_attn(const ushort* __restrict__ Qb,
                                              const ushort* __restrict__ Kb,
                                              const ushort* __restrict__ Vt,
                                              ushort* __restrict__ Ob) {
  __shared__ __align__(16) ushort Ks[64 * 136];
  __shared__ __align__(16) ushort Vs[128 * 72];
  __shared__ __align__(16) ushort Ps[4][32 * 72];
  const int tid = threadIdx.x;
  const int l = tid & 63, wid = tid >> 6;
  const int lr = l & 15, lq = l >> 4;

  const int bid = blockIdx.x;                  // grid = 1024
  const int swz = (bid & 7) * 128 + (bid >> 3);
  const int h = swz >> 6;
  const int q0 = (swz & 63) * 128 + wid * 32;

  bf16x8 aq[2][4];
#pragma unroll
  for (int m = 0; m < 2; m++) {
    const ushort* qp = Qb + (size_t)(q0 + m * 16 + lr) * DIM + h * HD;
#pragma unroll
    for (int kk = 0; kk < 4; kk++) aq[m][kk] = *(const bf16x8*)(qp + kk * 32 + lq * 8);
  }
  f32x4_t o[2][8];
#pragma unroll
  for (int m = 0; m < 2; m++)
#pragma unroll
    for (int i = 0; i < 8; i++) o[m][i] = f32x4_t{0.f, 0.f, 0.f, 0.f};
  float mrow[2][4], lrow[2][4];
#pragma unroll
  for (int m = 0; m < 2; m++)
#pragma unroll
    for (int r = 0; r < 4; r++) { mrow[m][r] = -1e30f; lrow[m][r] = 0.f; }

  auto loadK = [&](int kvb, int i) -> uint4 {
    const int c = i * 256 + tid, row = c >> 4, u = c & 15;
    return *(const uint4*)(Kb + (size_t)(kvb * 64 + row) * DIM + h * HD + u * 8);
  };
  auto loadV = [&](int kvb, int i) -> uint4 {
    const int c = i * 256 + tid, d = c >> 3, u = c & 7;
    return *(const uint4*)(Vt + (size_t)(h * HD + d) * S_SEQ + kvb * 64 + u * 8);
  };
  uint4 rk[4], rv[4];
#pragma unroll
  for (int i = 0; i < 4; i++) { rk[i] = loadK(0, i); rv[i] = loadV(0, i); }

  for (int kvb = 0; kvb < S_SEQ / 64; kvb++) {
    __syncthreads();
#pragma unroll
    for (int i = 0; i < 4; i++) {
      const int c = i * 256 + tid;
      *(uint4*)(&Ks[(c >> 4) * 136 + (c & 15) * 8]) = rk[i];
      *(uint4*)(&Vs[(c >> 3) * 72 + (c & 7) * 8]) = rv[i];
    }
    if (kvb + 1 < S_SEQ / 64) {
#pragma unroll
      for (int i = 0; i < 4; i++) { rk[i] = loadK(kvb + 1, i); rv[i] = loadV(kvb + 1, i); }
    }
    __syncthreads();

    f32x4_t s[2][4];
#pragma unroll
    for (int m = 0; m < 2; m++)
#pragma unroll
      for (int t = 0; t < 4; t++) s[m][t] = f32x4_t{0.f, 0.f, 0.f, 0.f};
#pragma unroll
    for (int t = 0; t < 4; t++) {
      bf16x8 bk[4];
#pragma unroll
      for (int kk = 0; kk < 4; kk++)
        bk[kk] = *(const bf16x8*)(&Ks[(t * 16 + lr) * 136 + kk * 32 + lq * 8]);
#pragma unroll
      for (int m = 0; m < 2; m++)
#pragma unroll
        for (int kk = 0; kk < 4; kk++)
          s[m][t] = __builtin_amdgcn_mfma_f32_16x16x32_bf16(aq[m][kk], bk[kk], s[m][t], 0, 0, 0);
    }
    float corr[2][4];
#pragma unroll
    for (int m = 0; m < 2; m++)
#pragma unroll
      for (int r = 0; r < 4; r++) {
        float rm = fmaxf(fmaxf(s[m][0][r], s[m][1][r]), fmaxf(s[m][2][r], s[m][3][r]));
#pragma unroll
        for (int mk = 1; mk < 16; mk <<= 1) rm = fmaxf(rm, __shfl_xor(rm, mk));
        const float mn = fmaxf(mrow[m][r], rm);
        corr[m][r] = __expf(mrow[m][r] - mn);
        mrow[m][r] = mn;
        float ps = 0.f;
#pragma unroll
        for (int t = 0; t < 4; t++) {
          const float p = __expf(s[m][t][r] - mn);
          s[m][t][r] = p; ps += p;
        }
#pragma unroll
        for (int mk = 1; mk < 16; mk <<= 1) ps += __shfl_xor(ps, mk);
        lrow[m][r] = lrow[m][r] * corr[m][r] + ps;
      }
    ushort* pw = &Ps[wid][0];
#pragma unroll
    for (int m = 0; m < 2; m++)
#pragma unroll
      for (int r = 0; r < 4; r++) {
        const int row = m * 16 + lq * 4 + r;
#pragma unroll
        for (int t = 0; t < 4; t++) pw[row * 72 + t * 16 + lr] = f2b(s[m][t][r]);
      }
#pragma unroll
    for (int m = 0; m < 2; m++)
#pragma unroll
      for (int dt = 0; dt < 8; dt++)
#pragma unroll
        for (int r = 0; r < 4; r++) o[m][dt][r] *= corr[m][r];
#pragma unroll
    for (int kq = 0; kq < 2; kq++) {
      bf16x8 pa[2];
#pragma unroll
      for (int m = 0; m < 2; m++)
        pa[m] = *(const bf16x8*)(&pw[(m * 16 + lr) * 72 + kq * 32 + lq * 8]);
#pragma unroll
      for (int dt = 0; dt < 8; dt++) {
        bf16x8 vb = *(const bf16x8*)(&Vs[(dt * 16 + lr) * 72 + kq * 32 + lq * 8]);
#pragma unroll
        for (int m = 0; m < 2; m++)
          o[m][dt] = __builtin_amdgcn_mfma_f32_16x16x32_bf16(pa[m], vb, o[m][dt], 0, 0, 0);
      }
    }
  }
#pragma unroll
  for (int m = 0; m < 2; m++)
#pragma unroll
    for (int r = 0; r < 4; r++) {
      const float inv = 1.0f / lrow[m][r];
      const int row = q0 + m * 16 + lq * 4 + r;
#pragma unroll
      for (int dt = 0; dt < 8; dt++)
        Ob[(size_t)row * DIM + h * HD + dt * 16 + lr] = f2b(o[m][dt][r] * inv);
    }
}

extern "C" void kernel_launch(void* const* d_in, const int* in_sizes, int n_in,
                              void* d_out, int out_size, void* d_ws, size_t ws_size,
                              hipStream_t stream) {
  const float* x   = (const float*)d_in[0];
  const float* ctx = (const float*)d_in[1];
  const float* Wq  = (const float*)d_in[2];
  const float* bq  = (const float*)d_in[3];
  const float* Wk  = (const float*)d_in[4];
  const float* bk  = (const float*)d_in[5];
  const float* Wv  = (const float*)d_in[6];
  const float* bv  = (const float*)d_in[7];
  const float* Wo  = (const float*)d_in[8];
  const float* bo  = (const float*)d_in[9];
  const float* gq  = (const float*)d_in[10];
  const float* gk  = (const float*)d_in[11];

  char* ws = (char*)d_ws;
  ushort* wqt   = (ushort*)(ws);                 // [2048][2048] bf16   8.39MB
  ushort* wkt   = (ushort*)(ws + 8388608);       // [2048][4096] bf16  16.78MB  } adjacent =>
  ushort* wvt   = (ushort*)(ws + 25165824);      // [2048][4096] bf16  16.78MB  } [4096][4096] KV
  ushort* wot   = (ushort*)(ws + 41943040);      // [2048][2048] bf16   8.39MB
  ushort* qb    = (ushort*)(ws + 50331648);      // [8192][2048] bf16  33.55MB (normalized Q)
  ushort* kb    = (ushort*)(ws + 83886080);      // [512][2048]  bf16   2.10MB (normalized K)
  ushort* vt    = (ushort*)(ws + 85983232);      // [2048][512]  bf16   2.10MB (V^T per-head)
  ushort* xb    = (ushort*)(ws + 88080384);      // [8192][2048] bf16  33.55MB (x cast)
  ushort* ctxb  = (ushort*)(ws + 88080384);      // [512][4096]  bf16   4.19MB (reuses xb)
  ushort* qraw  = (ushort*)(ws + 121634816);     // [8192][2048] bf16  33.55MB (pre-norm Q)
  ushort* kraw  = (ushort*)(ws + 121634816);     // [512][2048]  bf16   2.10MB (reuses qraw)
  ushort* attnb = (ushort*)(ws + 121634816);     // [8192][2048] bf16  33.55MB (reuses after K norm)

  // input casts + weight transposes
  k_cast<<<L_SEQ * DIM / 8 / 256, 256, 0, stream>>>(x, xb);
  k_tcast<<<dim3(DIM / 32, DIM / 32), dim3(32, 8), 0, stream>>>(Wq, wqt, DIM, DIM);
  k_tcast<<<dim3(DIM / 32, CTX / 32), dim3(32, 8), 0, stream>>>(Wk, wkt, CTX, DIM);
  k_tcast<<<dim3(DIM / 32, CTX / 32), dim3(32, 8), 0, stream>>>(Wv, wvt, CTX, DIM);
  k_tcast<<<dim3(DIM / 32, DIM / 32), dim3(32, 8), 0, stream>>>(Wo, wot, DIM, DIM);

  // Q path: q_raw = x@Wq + bq (bf16) -> rmsnorm*g_q with softmax scale folded
  k_gemm256<1><<<dim3(DIM / 256, L_SEQ / 256), 512, 0, stream>>>(xb, wqt, bq, qraw, L_SEQ, DIM, DIM);
  k_cast<<<S_SEQ * CTX / 8 / 256, 256, 0, stream>>>(ctx, ctxb);
  k_rmsnorm<<<L_SEQ, 256, 0, stream>>>(qraw, qb, gq, 0.08838834764831843f);
  // fused K+V projection: Bt = [Wk^T ; Wv^T] (adjacent in ws), N=4096
  k_gemm_bt<3><<<dim3(2 * DIM / 128, S_SEQ / 128), 256, 0, stream>>>(ctxb, wkt, bk, bv, kraw, vt, S_SEQ, 2 * DIM, CTX);
  k_rmsnorm<<<S_SEQ, 256, 0, stream>>>(kraw, kb, gk, 1.0f);
  // attention
  k_attn<<<L_SEQ / 128 * NH, 256, 0, stream>>>(qb, kb, vt, attnb);
  // out = attn @ Wo + bo (fp32)
  k_gemm256<0><<<dim3(DIM / 256, L_SEQ / 256), 512, 0, stream>>>(attnb, wot, bo, d_out, L_SEQ, DIM, DIM);
}

// Round 5
// 363.821 us; speedup vs baseline: 1.9226x; 1.1975x over previous
//
#include <hip/hip_runtime.h>
#include <hip/hip_bf16.h>
#include <stdint.h>

#define L_SEQ 8192
#define S_SEQ 512
#define DIM   2048
#define CTX   4096
#define NH    16
#define HD    128

typedef __bf16 bf16_t;
typedef bf16_t bf16x8 __attribute__((ext_vector_type(8)));
typedef float  f32x4_t __attribute__((ext_vector_type(4)));
typedef float  f32x16_t __attribute__((ext_vector_type(16)));

__device__ __forceinline__ ushort f2b(float f) {
  union { float f; uint32_t u; } v; v.f = f;
  uint32_t u = v.u;
  uint32_t r = (u + 0x7fffu + ((u >> 16) & 1u)) >> 16;
  return (ushort)r;
}
__device__ __forceinline__ uint32_t pk2(float a, float b) {
  return (uint32_t)f2b(a) | ((uint32_t)f2b(b) << 16);
}
__device__ __forceinline__ float b2f(ushort u) {
  union { uint32_t u; float f; } v; v.u = ((uint32_t)u) << 16;
  return v.f;
}
__device__ __forceinline__ void gll16(const ushort* g, ushort* l) {
  __builtin_amdgcn_global_load_lds((const __attribute__((address_space(1))) void*)g,
                                   (__attribute__((address_space(3))) void*)l, 16, 0, 0);
}

// ---------------- elementwise cast fp32 -> bf16 (8 elems/thread) ----------------
__global__ __launch_bounds__(256) void k_cast(const float* __restrict__ in,
                                              ushort* __restrict__ out) {
  const size_t i = ((size_t)blockIdx.x * 256 + threadIdx.x) * 8;
  float4 a = *(const float4*)(in + i);
  float4 b = *(const float4*)(in + i + 4);
  uint4 r;
  r.x = pk2(a.x, a.y); r.y = pk2(a.z, a.w);
  r.z = pk2(b.x, b.y); r.w = pk2(b.z, b.w);
  *(uint4*)(out + i) = r;
}

// ---------------- transpose + cast fp32 [K][N] -> bf16 [N][K] ----------------
__global__ __launch_bounds__(256) void k_tcast(const float* __restrict__ src,
                                               ushort* __restrict__ dst, int K, int N) {
  __shared__ float t[32][33];
  int tx = threadIdx.x, ty = threadIdx.y;
  int n0 = blockIdx.x * 32, k0 = blockIdx.y * 32;
#pragma unroll
  for (int i = 0; i < 4; i++)
    t[ty + 8 * i][tx] = src[(size_t)(k0 + ty + 8 * i) * N + n0 + tx];
  __syncthreads();
#pragma unroll
  for (int i = 0; i < 4; i++)
    dst[(size_t)(n0 + ty + 8 * i) * K + k0 + tx] = f2b(t[tx][ty + 8 * i]);
}

// ---------------- RMSNorm row kernel: bf16 [rows][2048] -> bf16, fused extra scale ----
__global__ __launch_bounds__(256) void k_rmsnorm(const ushort* __restrict__ in,
                                                 ushort* __restrict__ out,
                                                 const float* __restrict__ g, float scale) {
  const int row = blockIdx.x, tid = threadIdx.x;
  uint4 v = *(const uint4*)(in + (size_t)row * DIM + tid * 8);
  const uint32_t* vu = (const uint32_t*)&v;
  float f[8];
#pragma unroll
  for (int i = 0; i < 4; i++) {
    f[2 * i]     = b2f((ushort)(vu[i] & 0xffffu));
    f[2 * i + 1] = b2f((ushort)(vu[i] >> 16));
  }
  float s = 0.f;
#pragma unroll
  for (int i = 0; i < 8; i++) s += f[i] * f[i];
#pragma unroll
  for (int off = 32; off; off >>= 1) s += __shfl_down(s, off);
  __shared__ float wsum[4];
  __shared__ float rtot;
  if ((tid & 63) == 0) wsum[tid >> 6] = s;
  __syncthreads();
  if (tid == 0)
    rtot = rsqrtf((wsum[0] + wsum[1] + wsum[2] + wsum[3]) * (1.0f / DIM) + 1e-6f);
  __syncthreads();
  const float rms = rtot * scale;
  const float* gp = g + tid * 8;
  float4 g0 = *(const float4*)gp, g1 = *(const float4*)(gp + 4);
  ushort r[8];
  r[0] = f2b(f[0] * rms * g0.x); r[1] = f2b(f[1] * rms * g0.y);
  r[2] = f2b(f[2] * rms * g0.z); r[3] = f2b(f[3] * rms * g0.w);
  r[4] = f2b(f[4] * rms * g1.x); r[5] = f2b(f[5] * rms * g1.y);
  r[6] = f2b(f[6] * rms * g1.z); r[7] = f2b(f[7] * rms * g1.w);
  *(uint4*)(out + (size_t)row * DIM + tid * 8) = *(uint4*)r;
}

// ======================= 256x256 8-wave 4-phase GEMM =======================
template <int OUT_MODE>
__global__ __launch_bounds__(512, 2) void k_gemm256(const ushort* __restrict__ A,
                                                    const ushort* __restrict__ Bt,
                                                    const float* __restrict__ bias,
                                                    void* __restrict__ outp,
                                                    int M, int N, int K) {
  __shared__ __align__(16) ushort lds[65536];  // 128 KB
  const int tid = threadIdx.x;
  const int l = tid & 63, wid = tid >> 6;
  const int wm = wid >> 2, wn = wid & 3;
  const int lr = l & 15, lq = l >> 4;

  const int nwg = gridDim.x * gridDim.y;
  const int bid = blockIdx.y * gridDim.x + blockIdx.x;
  const int swz = (bid & 7) * (nwg >> 3) + (bid >> 3);
  const int m0 = (swz / gridDim.x) * 256, n0 = (swz % gridDim.x) * 256;

  f32x4_t acc[8][4];
#pragma unroll
  for (int i = 0; i < 8; i++)
#pragma unroll
    for (int j = 0; j < 4; j++) acc[i][j] = f32x4_t{0.f, 0.f, 0.f, 0.f};

  const int srow = l >> 3;
  const int schunk = ((l & 7) ^ (srow & 7)) * 8;
  auto stage = [&](int buf, int tile, int mat, int h) {
    const ushort* gp = mat ? Bt : A;
    const int rn0 = mat ? n0 : m0;
    const size_t r0 = (size_t)(rn0 + h * 128 + wid * 8 + srow);
    const ushort* g0 = gp + r0 * K + tile * 64 + schunk;
    ushort* l0 = &lds[buf * 32768 + mat * 16384 + (h * 128 + wid * 8) * 64];
    gll16(g0, l0);
    gll16(g0 + (size_t)64 * K, l0 + 64 * 64);
  };

  auto rdA = [&](int buf, int mf, int ks) -> bf16x8 {
    const int R = wm * 128 + mf * 16 + lr;
    return *(const bf16x8*)(&lds[buf * 32768 + R * 64 + (((ks * 4 + lq) ^ (R & 7)) * 8)]);
  };
  auto rdB = [&](int buf, int nf, int ks) -> bf16x8 {
    const int R = wn * 64 + nf * 16 + lr;
    return *(const bf16x8*)(&lds[buf * 32768 + 16384 + R * 64 + (((ks * 4 + lq) ^ (R & 7)) * 8)]);
  };

  const int NT = K >> 6;
  stage(0, 0, 0, 0); stage(0, 0, 0, 1); stage(0, 0, 1, 0); stage(0, 0, 1, 1);

  bf16x8 a[4][2], a2[4][2], b[2][2], b2[2][2];
  for (int kt = 0; kt < NT; kt++) {
    const int cur = kt & 1, nxt = cur ^ 1;
    const bool pf = (kt + 1 < NT);
    if (pf) { stage(nxt, kt + 1, 0, 0); asm volatile("s_waitcnt vmcnt(2)" ::: "memory"); }
    else    { asm volatile("s_waitcnt vmcnt(0)" ::: "memory"); }
    __builtin_amdgcn_sched_barrier(0);
    __builtin_amdgcn_s_barrier();
    __builtin_amdgcn_sched_barrier(0);
#pragma unroll
    for (int mf = 0; mf < 4; mf++) { a[mf][0] = rdA(cur, mf, 0); a[mf][1] = rdA(cur, mf, 1); }
#pragma unroll
    for (int nf = 0; nf < 2; nf++) { b[nf][0] = rdB(cur, nf, 0); b[nf][1] = rdB(cur, nf, 1); }
    __builtin_amdgcn_s_setprio(1);
#pragma unroll
    for (int mf = 0; mf < 4; mf++)
#pragma unroll
      for (int nf = 0; nf < 2; nf++) {
        acc[mf][nf] = __builtin_amdgcn_mfma_f32_16x16x32_bf16(a[mf][0], b[nf][0], acc[mf][nf], 0, 0, 0);
        acc[mf][nf] = __builtin_amdgcn_mfma_f32_16x16x32_bf16(a[mf][1], b[nf][1], acc[mf][nf], 0, 0, 0);
      }
    __builtin_amdgcn_s_setprio(0);
    __builtin_amdgcn_sched_barrier(0);
    __builtin_amdgcn_s_barrier();
    __builtin_amdgcn_sched_barrier(0);
#pragma unroll
    for (int mf = 0; mf < 4; mf++) { a2[mf][0] = rdA(cur, mf + 4, 0); a2[mf][1] = rdA(cur, mf + 4, 1); }
    if (pf) stage(nxt, kt + 1, 0, 1);
    __builtin_amdgcn_sched_barrier(0);
    __builtin_amdgcn_s_barrier();
    __builtin_amdgcn_sched_barrier(0);
    __builtin_amdgcn_s_setprio(1);
#pragma unroll
    for (int mf = 0; mf < 4; mf++)
#pragma unroll
      for (int nf = 0; nf < 2; nf++) {
        acc[mf + 4][nf] = __builtin_amdgcn_mfma_f32_16x16x32_bf16(a2[mf][0], b[nf][0], acc[mf + 4][nf], 0, 0, 0);
        acc[mf + 4][nf] = __builtin_amdgcn_mfma_f32_16x16x32_bf16(a2[mf][1], b[nf][1], acc[mf + 4][nf], 0, 0, 0);
      }
    __builtin_amdgcn_s_setprio(0);
    __builtin_amdgcn_sched_barrier(0);
    __builtin_amdgcn_s_barrier();
    __builtin_amdgcn_sched_barrier(0);
#pragma unroll
    for (int nf = 0; nf < 2; nf++) { b2[nf][0] = rdB(cur, nf + 2, 0); b2[nf][1] = rdB(cur, nf + 2, 1); }
    if (pf) stage(nxt, kt + 1, 1, 0);
    __builtin_amdgcn_sched_barrier(0);
    __builtin_amdgcn_s_barrier();
    __builtin_amdgcn_sched_barrier(0);
    __builtin_amdgcn_s_setprio(1);
#pragma unroll
    for (int mf = 0; mf < 4; mf++)
#pragma unroll
      for (int nf = 0; nf < 2; nf++) {
        acc[mf + 4][nf + 2] = __builtin_amdgcn_mfma_f32_16x16x32_bf16(a2[mf][0], b2[nf][0], acc[mf + 4][nf + 2], 0, 0, 0);
        acc[mf + 4][nf + 2] = __builtin_amdgcn_mfma_f32_16x16x32_bf16(a2[mf][1], b2[nf][1], acc[mf + 4][nf + 2], 0, 0, 0);
      }
    __builtin_amdgcn_s_setprio(0);
    __builtin_amdgcn_sched_barrier(0);
    __builtin_amdgcn_s_barrier();
    __builtin_amdgcn_sched_barrier(0);
#pragma unroll
    for (int mf = 0; mf < 4; mf++) { a[mf][0] = rdA(cur, mf, 0); a[mf][1] = rdA(cur, mf, 1); }
    if (pf) stage(nxt, kt + 1, 1, 1);
    __builtin_amdgcn_sched_barrier(0);
    __builtin_amdgcn_s_barrier();
    __builtin_amdgcn_sched_barrier(0);
    __builtin_amdgcn_s_setprio(1);
#pragma unroll
    for (int mf = 0; mf < 4; mf++)
#pragma unroll
      for (int nf = 0; nf < 2; nf++) {
        acc[mf][nf + 2] = __builtin_amdgcn_mfma_f32_16x16x32_bf16(a[mf][0], b2[nf][0], acc[mf][nf + 2], 0, 0, 0);
        acc[mf][nf + 2] = __builtin_amdgcn_mfma_f32_16x16x32_bf16(a[mf][1], b2[nf][1], acc[mf][nf + 2], 0, 0, 0);
      }
    __builtin_amdgcn_s_setprio(0);
    __builtin_amdgcn_sched_barrier(0);
    __builtin_amdgcn_s_barrier();
    __builtin_amdgcn_sched_barrier(0);
  }

#pragma unroll
  for (int nf = 0; nf < 4; nf++) {
    const int col = n0 + wn * 64 + nf * 16 + lr;
    const float bv = bias[col];
#pragma unroll
    for (int mf = 0; mf < 8; mf++) {
#pragma unroll
      for (int r = 0; r < 4; r++) {
        const int row = m0 + wm * 128 + mf * 16 + lq * 4 + r;
        const float v = acc[mf][nf][r] + bv;
        if constexpr (OUT_MODE == 0)
          ((float*)outp)[(size_t)row * N + col] = v;
        else
          ((ushort*)outp)[(size_t)row * N + col] = f2b(v);
      }
    }
  }
}

// ---------------- 128x128 GEMM (m97 structure) for the small KV projection -------
template <int OUT_MODE>
__global__ __launch_bounds__(256) void k_gemm_bt(const ushort* __restrict__ A,
                                                 const ushort* __restrict__ Bt,
                                                 const float* __restrict__ bias,
                                                 const float* __restrict__ bias2,
                                                 void* __restrict__ outp,
                                                 void* __restrict__ outp2,
                                                 int M, int N, int K) {
  __shared__ __align__(16) ushort As[128 * 32];
  __shared__ __align__(16) ushort Bs[128 * 32];
  const int tid = threadIdx.x;
  const int l = tid & 63, wid = tid >> 6;
  const int wr = wid >> 1, wc = wid & 1;
  const int lr = l & 15, lq = l >> 4;

  const int nwg = gridDim.x * gridDim.y;
  const int bid = blockIdx.y * gridDim.x + blockIdx.x;
  const int swz = (bid & 7) * (nwg >> 3) + (bid >> 3);
  const int m0 = (swz / gridDim.x) * 128, n0 = (swz % gridDim.x) * 128;

  f32x4_t acc[4][4];
#pragma unroll
  for (int i = 0; i < 4; i++)
#pragma unroll
    for (int j = 0; j < 4; j++) acc[i][j] = f32x4_t{0.f, 0.f, 0.f, 0.f};

  const int srow = l >> 2;
  const int scol = (l & 3) * 8;
  const ushort* ga0 = A  + (size_t)(m0 + wid * 16 + srow) * K + scol;
  const ushort* ga1 = A  + (size_t)(m0 + (4 + wid) * 16 + srow) * K + scol;
  const ushort* gb0 = Bt + (size_t)(n0 + wid * 16 + srow) * K + scol;
  const ushort* gb1 = Bt + (size_t)(n0 + (4 + wid) * 16 + srow) * K + scol;
  ushort* la0 = &As[wid * 512];
  ushort* la1 = &As[(4 + wid) * 512];
  ushort* lb0 = &Bs[wid * 512];
  ushort* lb1 = &Bs[(4 + wid) * 512];

  const int NT = K >> 5;
  for (int kt = 0; kt < NT; kt++) {
    __syncthreads();
    const int ko = kt * 32;
    gll16(ga0 + ko, la0);
    gll16(ga1 + ko, la1);
    gll16(gb0 + ko, lb0);
    gll16(gb1 + ko, lb1);
    __syncthreads();

    bf16x8 af[4], bfr[4];
#pragma unroll
    for (int mi = 0; mi < 4; mi++)
      af[mi] = *(const bf16x8*)(&As[(wr * 64 + mi * 16 + lr) * 32 + lq * 8]);
#pragma unroll
    for (int ni = 0; ni < 4; ni++)
      bfr[ni] = *(const bf16x8*)(&Bs[(wc * 64 + ni * 16 + lr) * 32 + lq * 8]);
#pragma unroll
    for (int mi = 0; mi < 4; mi++)
#pragma unroll
      for (int ni = 0; ni < 4; ni++)
        acc[mi][ni] = __builtin_amdgcn_mfma_f32_16x16x32_bf16(af[mi], bfr[ni], acc[mi][ni], 0, 0, 0);
  }

#pragma unroll
  for (int mi = 0; mi < 4; mi++) {
#pragma unroll
    for (int ni = 0; ni < 4; ni++) {
      const int col = n0 + wc * 64 + ni * 16 + lr;
      float bv;
      if constexpr (OUT_MODE == 3) bv = (col < DIM) ? bias[col] : bias2[col - DIM];
      else bv = bias[col];
#pragma unroll
      for (int r = 0; r < 4; r++) {
        const int row = m0 + wr * 64 + mi * 16 + lq * 4 + r;
        const float v = acc[mi][ni][r] + bv;
        if constexpr (OUT_MODE == 0)
          ((float*)outp)[(size_t)row * N + col] = v;
        else if constexpr (OUT_MODE == 1)
          ((ushort*)outp)[(size_t)row * N + col] = f2b(v);
        else {
          if (col < DIM) ((ushort*)outp)[(size_t)row * DIM + col] = f2b(v);
          else ((ushort*)outp2)[(size_t)(col - DIM) * M + row] = f2b(v);  // V^T
        }
      }
    }
  }
}

// ============ Flash attention, swapped-operand 32x32x16 structure ============
// 4 waves x 32 q-rows. QK^T computed as mfma(K, Q) -> lane owns q-row (l&31),
// 32 kv scores in regs; softmax in-register (1 shfl per reduction). PV computed
// as mfma(V^T, P^T) -> O^T with same lane->q map; P^T B-frags built in-register
// via pk2 + shfl_xor(32). K/V LDS tiles XOR-swizzled (inverse-swizzle on the
// global_load_lds source, swizzle on ds_read).
__global__ __launch_bounds__(256) void k_attn(const ushort* __restrict__ Qb,
                                              const ushort* __restrict__ Kb,
                                              const ushort* __restrict__ Vt,
                                              ushort* __restrict__ Ob) {
  __shared__ __align__(16) ushort smem[16384];  // 32KB: Ks [64][128] + Vs [128][64]
  ushort* Ks = smem;
  ushort* Vs = smem + 64 * 128;

  const int tid = threadIdx.x;
  const int l = tid & 63, wid = tid >> 6;
  const int lo = l & 31, hi = l >> 5;

  const int bid = blockIdx.x;                  // grid = 1024
  const int swz = (bid & 7) * 128 + (bid >> 3);
  const int h = swz >> 6;
  const int q0 = (swz & 63) * 128 + wid * 32;

  // Q fragments (B operand): lane holds Q[q = lo][d = ds*16 + hi*8 + 0..7]
  bf16x8 qf[8];
  {
    const ushort* qp = Qb + (size_t)(q0 + lo) * DIM + h * HD + hi * 8;
#pragma unroll
    for (int ds = 0; ds < 8; ds++) qf[ds] = *(const bf16x8*)(qp + ds * 16);
  }

  f32x16_t o[4] = {};          // O^T: lane q = lo, d = nt*32 + crow(r,hi)
  float m_run = -1e30f, l_run = 0.f;

  for (int kvb = 0; kvb < S_SEQ / 64; kvb++) {
    __syncthreads();  // previous tile's reads done
    // stage K: dest chunk (row, cs) <- global chunk (row, cs ^ (row&7))
#pragma unroll
    for (int i = 0; i < 4; i++) {
      const int c = i * 256 + tid, row = c >> 4, cs = c & 15;
      gll16(Kb + (size_t)(kvb * 64 + row) * DIM + h * HD + ((cs ^ (row & 7)) * 8),
            Ks + c * 8);
    }
    // stage V^T: dest chunk (row, cs) <- global chunk (row, cs ^ (row&7))
#pragma unroll
    for (int i = 0; i < 4; i++) {
      const int c = i * 256 + tid, row = c >> 3, cs = c & 7;
      gll16(Vt + (size_t)(h * HD + row) * S_SEQ + kvb * 64 + ((cs ^ (row & 7)) * 8),
            Vs + c * 8);
    }
    __syncthreads();  // drains vmcnt(0): tile resident

    // ---- QK^T (swapped): sA = S^T[kv 0-31][q], sB = S^T[kv 32-63][q] ----
    f32x16_t sA = {}, sB = {};
#pragma unroll
    for (int ds = 0; ds < 8; ds++) {
      const int ch = ((hi + ds * 2) ^ (lo & 7)) * 8;
      bf16x8 kA = *(const bf16x8*)(Ks + lo * 128 + ch);
      bf16x8 kB = *(const bf16x8*)(Ks + (32 + lo) * 128 + ch);
      sA = __builtin_amdgcn_mfma_f32_32x32x16_bf16(kA, qf[ds], sA, 0, 0, 0);
      sB = __builtin_amdgcn_mfma_f32_32x32x16_bf16(kB, qf[ds], sB, 0, 0, 0);
    }

    // ---- online softmax, fully lane-local + one shfl per reduction ----
    float p[32];
#pragma unroll
    for (int i = 0; i < 16; i++) { p[i] = sA[i]; p[16 + i] = sB[i]; }
    float pm = p[0];
#pragma unroll
    for (int i = 1; i < 32; i++) pm = fmaxf(pm, p[i]);
    pm = fmaxf(pm, __shfl_xor(pm, 32));
    const float mn = fmaxf(m_run, pm);
    const float corr = __expf(m_run - mn);
    m_run = mn;
    float ps = 0.f;
#pragma unroll
    for (int i = 0; i < 32; i++) { p[i] = __expf(p[i] - mn); ps += p[i]; }
    ps += __shfl_xor(ps, 32);
    l_run = l_run * corr + ps;
#pragma unroll
    for (int nt = 0; nt < 4; nt++) o[nt] *= corr;

    // ---- build P^T B-frags: pf[s] covers kv = s*16 + hi*8 + 0..7 ----
    uint32_t c[16];
#pragma unroll
    for (int j = 0; j < 16; j++) c[j] = pk2(p[2 * j], p[2 * j + 1]);
    bf16x8 pf[4];
#pragma unroll
    for (int s = 0; s < 4; s++) {
      const uint32_t ca = c[4 * s], cb = c[4 * s + 1], cc = c[4 * s + 2], cd = c[4 * s + 3];
      const uint32_t sa = __shfl_xor(ca, 32), sb = __shfl_xor(cb, 32);
      const uint32_t sc = __shfl_xor(cc, 32), sd = __shfl_xor(cd, 32);
      union { uint32_t u[4]; bf16x8 v; } f;
      f.u[0] = hi ? sc : ca; f.u[1] = hi ? sd : cb;
      f.u[2] = hi ? cc : sa; f.u[3] = hi ? cd : sb;
      pf[s] = f.v;
    }

    // ---- PV (swapped): o[nt] += V^T-frag x P^T-frag ----
#pragma unroll
    for (int nt = 0; nt < 4; nt++) {
      const int vrow = nt * 32 + lo;
#pragma unroll
      for (int s = 0; s < 4; s++) {
        bf16x8 vf = *(const bf16x8*)(Vs + vrow * 64 + (((s * 2 + hi) ^ (lo & 7)) * 8));
        o[nt] = __builtin_amdgcn_mfma_f32_32x32x16_bf16(vf, pf[s], o[nt], 0, 0, 0);
      }
    }
  }

  // ---- epilogue: normalize, transpose O^T->O via per-wave LDS, coalesced store ----
  const float inv = 1.0f / l_run;
#pragma unroll
  for (int nt = 0; nt < 4; nt++) o[nt] *= inv;

  __syncthreads();  // all waves done with Ks/Vs; reuse as transpose buffers
  float* tb = (float*)smem + wid * (32 * 33);  // 4224B per wave
  const int q2 = l >> 1, dh = (l & 1) * 16;
#pragma unroll
  for (int nt = 0; nt < 4; nt++) {
#pragma unroll
    for (int r = 0; r < 16; r++)
      tb[lo * 33 + ((r & 3) + 8 * (r >> 2) + 4 * hi)] = o[nt][r];
    asm volatile("s_waitcnt lgkmcnt(0)" ::: "memory");
    __builtin_amdgcn_sched_barrier(0);
    ushort tmp[16];
#pragma unroll
    for (int j = 0; j < 16; j++) tmp[j] = f2b(tb[q2 * 33 + dh + j]);
    asm volatile("s_waitcnt lgkmcnt(0)" ::: "memory");
    __builtin_amdgcn_sched_barrier(0);
    const size_t oaddr = (size_t)(q0 + q2) * DIM + h * HD + nt * 32 + dh;
    *(uint4*)(Ob + oaddr) = *(uint4*)tmp;
    *(uint4*)(Ob + oaddr + 8) = *(uint4*)(tmp + 8);
  }
}

extern "C" void kernel_launch(void* const* d_in, const int* in_sizes, int n_in,
                              void* d_out, int out_size, void* d_ws, size_t ws_size,
                              hipStream_t stream) {
  const float* x   = (const float*)d_in[0];
  const float* ctx = (const float*)d_in[1];
  const float* Wq  = (const float*)d_in[2];
  const float* bq  = (const float*)d_in[3];
  const float* Wk  = (const float*)d_in[4];
  const float* bk  = (const float*)d_in[5];
  const float* Wv  = (const float*)d_in[6];
  const float* bv  = (const float*)d_in[7];
  const float* Wo  = (const float*)d_in[8];
  const float* bo  = (const float*)d_in[9];
  const float* gq  = (const float*)d_in[10];
  const float* gk  = (const float*)d_in[11];

  char* ws = (char*)d_ws;
  ushort* wqt   = (ushort*)(ws);                 // [2048][2048] bf16   8.39MB
  ushort* wkt   = (ushort*)(ws + 8388608);       // [2048][4096] bf16  16.78MB  } adjacent =>
  ushort* wvt   = (ushort*)(ws + 25165824);      // [2048][4096] bf16  16.78MB  } [4096][4096] KV
  ushort* wot   = (ushort*)(ws + 41943040);      // [2048][2048] bf16   8.39MB
  ushort* qb    = (ushort*)(ws + 50331648);      // [8192][2048] bf16  33.55MB (normalized Q)
  ushort* kb    = (ushort*)(ws + 83886080);      // [512][2048]  bf16   2.10MB (normalized K)
  ushort* vt    = (ushort*)(ws + 85983232);      // [2048][512]  bf16   2.10MB (V^T per-head)
  ushort* xb    = (ushort*)(ws + 88080384);      // [8192][2048] bf16  33.55MB (x cast)
  ushort* ctxb  = (ushort*)(ws + 88080384);      // [512][4096]  bf16   4.19MB (reuses xb)
  ushort* qraw  = (ushort*)(ws + 121634816);     // [8192][2048] bf16  33.55MB (pre-norm Q)
  ushort* kraw  = (ushort*)(ws + 121634816);     // [512][2048]  bf16   2.10MB (reuses qraw)
  ushort* attnb = (ushort*)(ws + 121634816);     // [8192][2048] bf16  33.55MB (reuses after K norm)

  // input casts + weight transposes
  k_cast<<<L_SEQ * DIM / 8 / 256, 256, 0, stream>>>(x, xb);
  k_tcast<<<dim3(DIM / 32, DIM / 32), dim3(32, 8), 0, stream>>>(Wq, wqt, DIM, DIM);
  k_tcast<<<dim3(DIM / 32, CTX / 32), dim3(32, 8), 0, stream>>>(Wk, wkt, CTX, DIM);
  k_tcast<<<dim3(DIM / 32, CTX / 32), dim3(32, 8), 0, stream>>>(Wv, wvt, CTX, DIM);
  k_tcast<<<dim3(DIM / 32, DIM / 32), dim3(32, 8), 0, stream>>>(Wo, wot, DIM, DIM);

  // Q path: q_raw = x@Wq + bq (bf16) -> rmsnorm*g_q with softmax scale folded
  k_gemm256<1><<<dim3(DIM / 256, L_SEQ / 256), 512, 0, stream>>>(xb, wqt, bq, qraw, L_SEQ, DIM, DIM);
  k_cast<<<S_SEQ * CTX / 8 / 256, 256, 0, stream>>>(ctx, ctxb);
  k_rmsnorm<<<L_SEQ, 256, 0, stream>>>(qraw, qb, gq, 0.08838834764831843f);
  // fused K+V projection: Bt = [Wk^T ; Wv^T] (adjacent in ws), N=4096
  k_gemm_bt<3><<<dim3(2 * DIM / 128, S_SEQ / 128), 256, 0, stream>>>(ctxb, wkt, bk, bv, kraw, vt, S_SEQ, 2 * DIM, CTX);
  k_rmsnorm<<<S_SEQ, 256, 0, stream>>>(kraw, kb, gk, 1.0f);
  // attention (swapped-operand 32x32 structure)
  k_attn<<<L_SEQ / 128 * NH, 256, 0, stream>>>(qb, kb, vt, attnb);
  // out = attn @ Wo + bo (fp32)
  k_gemm256<0><<<dim3(DIM / 256, L_SEQ / 256), 512, 0, stream>>>(attnb, wot, bo, d_out, L_SEQ, DIM, DIM);
}

// Round 6
// 355.469 us; speedup vs baseline: 1.9678x; 1.0235x over previous
//
#include <hip/hip_runtime.h>
#include <hip/hip_bf16.h>
#include <stdint.h>

#define L_SEQ 8192
#define S_SEQ 512
#define DIM   2048
#define CTX   4096
#define NH    16
#define HD    128

typedef __bf16 bf16_t;
typedef bf16_t bf16x8 __attribute__((ext_vector_type(8)));
typedef float  f32x4_t __attribute__((ext_vector_type(4)));
typedef float  f32x16_t __attribute__((ext_vector_type(16)));

__device__ __forceinline__ ushort f2b(float f) {
  union { float f; uint32_t u; } v; v.f = f;
  uint32_t u = v.u;
  uint32_t r = (u + 0x7fffu + ((u >> 16) & 1u)) >> 16;
  return (ushort)r;
}
__device__ __forceinline__ uint32_t pk2(float a, float b) {
  return (uint32_t)f2b(a) | ((uint32_t)f2b(b) << 16);
}
__device__ __forceinline__ float b2f(ushort u) {
  union { uint32_t u; float f; } v; v.u = ((uint32_t)u) << 16;
  return v.f;
}
__device__ __forceinline__ void gll16(const ushort* g, ushort* l) {
  __builtin_amdgcn_global_load_lds((const __attribute__((address_space(1))) void*)g,
                                   (__attribute__((address_space(3))) void*)l, 16, 0, 0);
}

// ---------------- elementwise cast fp32 -> bf16 (8 elems/thread) ----------------
__global__ __launch_bounds__(256) void k_cast(const float* __restrict__ in,
                                              ushort* __restrict__ out) {
  const size_t i = ((size_t)blockIdx.x * 256 + threadIdx.x) * 8;
  float4 a = *(const float4*)(in + i);
  float4 b = *(const float4*)(in + i + 4);
  uint4 r;
  r.x = pk2(a.x, a.y); r.y = pk2(a.z, a.w);
  r.z = pk2(b.x, b.y); r.w = pk2(b.z, b.w);
  *(uint4*)(out + i) = r;
}

// ---------------- transpose + cast fp32 [K][N] -> bf16 [N][K] ----------------
__global__ __launch_bounds__(256) void k_tcast(const float* __restrict__ src,
                                               ushort* __restrict__ dst, int K, int N) {
  __shared__ float t[32][33];
  int tx = threadIdx.x, ty = threadIdx.y;
  int n0 = blockIdx.x * 32, k0 = blockIdx.y * 32;
#pragma unroll
  for (int i = 0; i < 4; i++)
    t[ty + 8 * i][tx] = src[(size_t)(k0 + ty + 8 * i) * N + n0 + tx];
  __syncthreads();
#pragma unroll
  for (int i = 0; i < 4; i++)
    dst[(size_t)(n0 + ty + 8 * i) * K + k0 + tx] = f2b(t[tx][ty + 8 * i]);
}

// ---------------- RMSNorm row kernel: bf16 [rows][2048] -> bf16, fused extra scale ----
__global__ __launch_bounds__(256) void k_rmsnorm(const ushort* __restrict__ in,
                                                 ushort* __restrict__ out,
                                                 const float* __restrict__ g, float scale) {
  const int row = blockIdx.x, tid = threadIdx.x;
  uint4 v = *(const uint4*)(in + (size_t)row * DIM + tid * 8);
  const uint32_t* vu = (const uint32_t*)&v;
  float f[8];
#pragma unroll
  for (int i = 0; i < 4; i++) {
    f[2 * i]     = b2f((ushort)(vu[i] & 0xffffu));
    f[2 * i + 1] = b2f((ushort)(vu[i] >> 16));
  }
  float s = 0.f;
#pragma unroll
  for (int i = 0; i < 8; i++) s += f[i] * f[i];
#pragma unroll
  for (int off = 32; off; off >>= 1) s += __shfl_down(s, off);
  __shared__ float wsum[4];
  __shared__ float rtot;
  if ((tid & 63) == 0) wsum[tid >> 6] = s;
  __syncthreads();
  if (tid == 0)
    rtot = rsqrtf((wsum[0] + wsum[1] + wsum[2] + wsum[3]) * (1.0f / DIM) + 1e-6f);
  __syncthreads();
  const float rms = rtot * scale;
  const float* gp = g + tid * 8;
  float4 g0 = *(const float4*)gp, g1 = *(const float4*)(gp + 4);
  ushort r[8];
  r[0] = f2b(f[0] * rms * g0.x); r[1] = f2b(f[1] * rms * g0.y);
  r[2] = f2b(f[2] * rms * g0.z); r[3] = f2b(f[3] * rms * g0.w);
  r[4] = f2b(f[4] * rms * g1.x); r[5] = f2b(f[5] * rms * g1.y);
  r[6] = f2b(f[6] * rms * g1.z); r[7] = f2b(f[7] * rms * g1.w);
  *(uint4*)(out + (size_t)row * DIM + tid * 8) = *(uint4*)r;
}

// ======================= 256x256 8-wave 4-phase GEMM =======================
template <int OUT_MODE>
__global__ __launch_bounds__(512, 2) void k_gemm256(const ushort* __restrict__ A,
                                                    const ushort* __restrict__ Bt,
                                                    const float* __restrict__ bias,
                                                    void* __restrict__ outp,
                                                    int M, int N, int K) {
  __shared__ __align__(16) ushort lds[65536];  // 128 KB
  const int tid = threadIdx.x;
  const int l = tid & 63, wid = tid >> 6;
  const int wm = wid >> 2, wn = wid & 3;
  const int lr = l & 15, lq = l >> 4;

  const int nwg = gridDim.x * gridDim.y;
  const int bid = blockIdx.y * gridDim.x + blockIdx.x;
  const int swz = (bid & 7) * (nwg >> 3) + (bid >> 3);
  const int m0 = (swz / gridDim.x) * 256, n0 = (swz % gridDim.x) * 256;

  f32x4_t acc[8][4];
#pragma unroll
  for (int i = 0; i < 8; i++)
#pragma unroll
    for (int j = 0; j < 4; j++) acc[i][j] = f32x4_t{0.f, 0.f, 0.f, 0.f};

  const int srow = l >> 3;
  const int schunk = ((l & 7) ^ (srow & 7)) * 8;
  auto stage = [&](int buf, int tile, int mat, int h) {
    const ushort* gp = mat ? Bt : A;
    const int rn0 = mat ? n0 : m0;
    const size_t r0 = (size_t)(rn0 + h * 128 + wid * 8 + srow);
    const ushort* g0 = gp + r0 * K + tile * 64 + schunk;
    ushort* l0 = &lds[buf * 32768 + mat * 16384 + (h * 128 + wid * 8) * 64];
    gll16(g0, l0);
    gll16(g0 + (size_t)64 * K, l0 + 64 * 64);
  };

  auto rdA = [&](int buf, int mf, int ks) -> bf16x8 {
    const int R = wm * 128 + mf * 16 + lr;
    return *(const bf16x8*)(&lds[buf * 32768 + R * 64 + (((ks * 4 + lq) ^ (R & 7)) * 8)]);
  };
  auto rdB = [&](int buf, int nf, int ks) -> bf16x8 {
    const int R = wn * 64 + nf * 16 + lr;
    return *(const bf16x8*)(&lds[buf * 32768 + 16384 + R * 64 + (((ks * 4 + lq) ^ (R & 7)) * 8)]);
  };

  const int NT = K >> 6;
  stage(0, 0, 0, 0); stage(0, 0, 0, 1); stage(0, 0, 1, 0); stage(0, 0, 1, 1);

  bf16x8 a[4][2], a2[4][2], b[2][2], b2[2][2];
  for (int kt = 0; kt < NT; kt++) {
    const int cur = kt & 1, nxt = cur ^ 1;
    const bool pf = (kt + 1 < NT);
    if (pf) { stage(nxt, kt + 1, 0, 0); asm volatile("s_waitcnt vmcnt(2)" ::: "memory"); }
    else    { asm volatile("s_waitcnt vmcnt(0)" ::: "memory"); }
    __builtin_amdgcn_sched_barrier(0);
    __builtin_amdgcn_s_barrier();
    __builtin_amdgcn_sched_barrier(0);
#pragma unroll
    for (int mf = 0; mf < 4; mf++) { a[mf][0] = rdA(cur, mf, 0); a[mf][1] = rdA(cur, mf, 1); }
#pragma unroll
    for (int nf = 0; nf < 2; nf++) { b[nf][0] = rdB(cur, nf, 0); b[nf][1] = rdB(cur, nf, 1); }
    __builtin_amdgcn_s_setprio(1);
#pragma unroll
    for (int mf = 0; mf < 4; mf++)
#pragma unroll
      for (int nf = 0; nf < 2; nf++) {
        acc[mf][nf] = __builtin_amdgcn_mfma_f32_16x16x32_bf16(a[mf][0], b[nf][0], acc[mf][nf], 0, 0, 0);
        acc[mf][nf] = __builtin_amdgcn_mfma_f32_16x16x32_bf16(a[mf][1], b[nf][1], acc[mf][nf], 0, 0, 0);
      }
    __builtin_amdgcn_s_setprio(0);
    __builtin_amdgcn_sched_barrier(0);
    __builtin_amdgcn_s_barrier();
    __builtin_amdgcn_sched_barrier(0);
#pragma unroll
    for (int mf = 0; mf < 4; mf++) { a2[mf][0] = rdA(cur, mf + 4, 0); a2[mf][1] = rdA(cur, mf + 4, 1); }
    if (pf) stage(nxt, kt + 1, 0, 1);
    __builtin_amdgcn_sched_barrier(0);
    __builtin_amdgcn_s_barrier();
    __builtin_amdgcn_sched_barrier(0);
    __builtin_amdgcn_s_setprio(1);
#pragma unroll
    for (int mf = 0; mf < 4; mf++)
#pragma unroll
      for (int nf = 0; nf < 2; nf++) {
        acc[mf + 4][nf] = __builtin_amdgcn_mfma_f32_16x16x32_bf16(a2[mf][0], b[nf][0], acc[mf + 4][nf], 0, 0, 0);
        acc[mf + 4][nf] = __builtin_amdgcn_mfma_f32_16x16x32_bf16(a2[mf][1], b[nf][1], acc[mf + 4][nf], 0, 0, 0);
      }
    __builtin_amdgcn_s_setprio(0);
    __builtin_amdgcn_sched_barrier(0);
    __builtin_amdgcn_s_barrier();
    __builtin_amdgcn_sched_barrier(0);
#pragma unroll
    for (int nf = 0; nf < 2; nf++) { b2[nf][0] = rdB(cur, nf + 2, 0); b2[nf][1] = rdB(cur, nf + 2, 1); }
    if (pf) stage(nxt, kt + 1, 1, 0);
    __builtin_amdgcn_sched_barrier(0);
    __builtin_amdgcn_s_barrier();
    __builtin_amdgcn_sched_barrier(0);
    __builtin_amdgcn_s_setprio(1);
#pragma unroll
    for (int mf = 0; mf < 4; mf++)
#pragma unroll
      for (int nf = 0; nf < 2; nf++) {
        acc[mf + 4][nf + 2] = __builtin_amdgcn_mfma_f32_16x16x32_bf16(a2[mf][0], b2[nf][0], acc[mf + 4][nf + 2], 0, 0, 0);
        acc[mf + 4][nf + 2] = __builtin_amdgcn_mfma_f32_16x16x32_bf16(a2[mf][1], b2[nf][1], acc[mf + 4][nf + 2], 0, 0, 0);
      }
    __builtin_amdgcn_s_setprio(0);
    __builtin_amdgcn_sched_barrier(0);
    __builtin_amdgcn_s_barrier();
    __builtin_amdgcn_sched_barrier(0);
#pragma unroll
    for (int mf = 0; mf < 4; mf++) { a[mf][0] = rdA(cur, mf, 0); a[mf][1] = rdA(cur, mf, 1); }
    if (pf) stage(nxt, kt + 1, 1, 1);
    __builtin_amdgcn_sched_barrier(0);
    __builtin_amdgcn_s_barrier();
    __builtin_amdgcn_sched_barrier(0);
    __builtin_amdgcn_s_setprio(1);
#pragma unroll
    for (int mf = 0; mf < 4; mf++)
#pragma unroll
      for (int nf = 0; nf < 2; nf++) {
        acc[mf][nf + 2] = __builtin_amdgcn_mfma_f32_16x16x32_bf16(a[mf][0], b2[nf][0], acc[mf][nf + 2], 0, 0, 0);
        acc[mf][nf + 2] = __builtin_amdgcn_mfma_f32_16x16x32_bf16(a[mf][1], b2[nf][1], acc[mf][nf + 2], 0, 0, 0);
      }
    __builtin_amdgcn_s_setprio(0);
    __builtin_amdgcn_sched_barrier(0);
    __builtin_amdgcn_s_barrier();
    __builtin_amdgcn_sched_barrier(0);
  }

#pragma unroll
  for (int nf = 0; nf < 4; nf++) {
    const int col = n0 + wn * 64 + nf * 16 + lr;
    const float bv = bias[col];
#pragma unroll
    for (int mf = 0; mf < 8; mf++) {
#pragma unroll
      for (int r = 0; r < 4; r++) {
        const int row = m0 + wm * 128 + mf * 16 + lq * 4 + r;
        const float v = acc[mf][nf][r] + bv;
        if constexpr (OUT_MODE == 0)
          ((float*)outp)[(size_t)row * N + col] = v;
        else
          ((ushort*)outp)[(size_t)row * N + col] = f2b(v);
      }
    }
  }
}

// ------- 128x128 GEMM, double-buffered LDS + counted vmcnt (KV projection) -------
// Per iter: stage next tile into buf^1 -> vmcnt(4) (waits only current tile's
// loads, issued one iter earlier; next tile's 4 stay in flight) -> barrier ->
// ds_read+MFMA -> barrier (reads done before buf is overwritten next iter).
// OUT_MODE 3: split KV epilogue — cols<DIM -> bf16 [M,DIM]; cols>=DIM -> [N-DIM][M]^T.
template <int OUT_MODE>
__global__ __launch_bounds__(256) void k_gemm_bt(const ushort* __restrict__ A,
                                                 const ushort* __restrict__ Bt,
                                                 const float* __restrict__ bias,
                                                 const float* __restrict__ bias2,
                                                 void* __restrict__ outp,
                                                 void* __restrict__ outp2,
                                                 int M, int N, int K) {
  __shared__ __align__(16) ushort As[2 * 128 * 32];  // double-buffered, linear
  __shared__ __align__(16) ushort Bs[2 * 128 * 32];
  const int tid = threadIdx.x;
  const int l = tid & 63, wid = tid >> 6;
  const int wr = wid >> 1, wc = wid & 1;
  const int lr = l & 15, lq = l >> 4;

  const int nwg = gridDim.x * gridDim.y;
  const int bid = blockIdx.y * gridDim.x + blockIdx.x;
  const int swz = (bid & 7) * (nwg >> 3) + (bid >> 3);
  const int m0 = (swz / gridDim.x) * 128, n0 = (swz % gridDim.x) * 128;

  f32x4_t acc[4][4];
#pragma unroll
  for (int i = 0; i < 4; i++)
#pragma unroll
    for (int j = 0; j < 4; j++) acc[i][j] = f32x4_t{0.f, 0.f, 0.f, 0.f};

  const int srow = l >> 2;
  const int scol = (l & 3) * 8;
  const ushort* ga0 = A  + (size_t)(m0 + wid * 16 + srow) * K + scol;
  const ushort* ga1 = A  + (size_t)(m0 + (4 + wid) * 16 + srow) * K + scol;
  const ushort* gb0 = Bt + (size_t)(n0 + wid * 16 + srow) * K + scol;
  const ushort* gb1 = Bt + (size_t)(n0 + (4 + wid) * 16 + srow) * K + scol;

  auto stageAB = [&](int buf, int kt) {
    const int ko = kt * 32;
    gll16(ga0 + ko, &As[buf * 4096 + wid * 512]);
    gll16(ga1 + ko, &As[buf * 4096 + (4 + wid) * 512]);
    gll16(gb0 + ko, &Bs[buf * 4096 + wid * 512]);
    gll16(gb1 + ko, &Bs[buf * 4096 + (4 + wid) * 512]);
  };

  const int NT = K >> 5;
  stageAB(0, 0);
  for (int kt = 0; kt < NT; kt++) {
    const int cur = kt & 1;
    const bool pf = (kt + 1 < NT);
    if (pf) { stageAB(cur ^ 1, kt + 1); asm volatile("s_waitcnt vmcnt(4)" ::: "memory"); }
    else    { asm volatile("s_waitcnt vmcnt(0)" ::: "memory"); }
    __builtin_amdgcn_sched_barrier(0);
    __builtin_amdgcn_s_barrier();    // current tile resident (every wave drained its own)
    __builtin_amdgcn_sched_barrier(0);

    bf16x8 af[4], bfr[4];
#pragma unroll
    for (int mi = 0; mi < 4; mi++)
      af[mi] = *(const bf16x8*)(&As[cur * 4096 + (wr * 64 + mi * 16 + lr) * 32 + lq * 8]);
#pragma unroll
    for (int ni = 0; ni < 4; ni++)
      bfr[ni] = *(const bf16x8*)(&Bs[cur * 4096 + (wc * 64 + ni * 16 + lr) * 32 + lq * 8]);
#pragma unroll
    for (int mi = 0; mi < 4; mi++)
#pragma unroll
      for (int ni = 0; ni < 4; ni++)
        acc[mi][ni] = __builtin_amdgcn_mfma_f32_16x16x32_bf16(af[mi], bfr[ni], acc[mi][ni], 0, 0, 0);
    __builtin_amdgcn_sched_barrier(0);
    __builtin_amdgcn_s_barrier();    // reads of cur done before next iter overwrites it
    __builtin_amdgcn_sched_barrier(0);
  }

#pragma unroll
  for (int mi = 0; mi < 4; mi++) {
#pragma unroll
    for (int ni = 0; ni < 4; ni++) {
      const int col = n0 + wc * 64 + ni * 16 + lr;
      float bv;
      if constexpr (OUT_MODE == 3) bv = (col < DIM) ? bias[col] : bias2[col - DIM];
      else bv = bias[col];
#pragma unroll
      for (int r = 0; r < 4; r++) {
        const int row = m0 + wr * 64 + mi * 16 + lq * 4 + r;
        const float v = acc[mi][ni][r] + bv;
        if constexpr (OUT_MODE == 0)
          ((float*)outp)[(size_t)row * N + col] = v;
        else if constexpr (OUT_MODE == 1)
          ((ushort*)outp)[(size_t)row * N + col] = f2b(v);
        else {
          if (col < DIM) ((ushort*)outp)[(size_t)row * DIM + col] = f2b(v);
          else ((ushort*)outp2)[(size_t)(col - DIM) * M + row] = f2b(v);  // V^T
        }
      }
    }
  }
}

// ============ Flash attention, swapped-operand 32x32x16 structure ============
__global__ __launch_bounds__(256) void k_attn(const ushort* __restrict__ Qb,
                                              const ushort* __restrict__ Kb,
                                              const ushort* __restrict__ Vt,
                                              ushort* __restrict__ Ob) {
  __shared__ __align__(16) ushort smem[16384];  // 32KB: Ks [64][128] + Vs [128][64]
  ushort* Ks = smem;
  ushort* Vs = smem + 64 * 128;

  const int tid = threadIdx.x;
  const int l = tid & 63, wid = tid >> 6;
  const int lo = l & 31, hi = l >> 5;

  const int bid = blockIdx.x;                  // grid = 1024
  const int swz = (bid & 7) * 128 + (bid >> 3);
  const int h = swz >> 6;
  const int q0 = (swz & 63) * 128 + wid * 32;

  bf16x8 qf[8];
  {
    const ushort* qp = Qb + (size_t)(q0 + lo) * DIM + h * HD + hi * 8;
#pragma unroll
    for (int ds = 0; ds < 8; ds++) qf[ds] = *(const bf16x8*)(qp + ds * 16);
  }

  f32x16_t o[4] = {};          // O^T: lane q = lo, d = nt*32 + crow(r,hi)
  float m_run = -1e30f, l_run = 0.f;

  for (int kvb = 0; kvb < S_SEQ / 64; kvb++) {
    __syncthreads();
#pragma unroll
    for (int i = 0; i < 4; i++) {
      const int c = i * 256 + tid, row = c >> 4, cs = c & 15;
      gll16(Kb + (size_t)(kvb * 64 + row) * DIM + h * HD + ((cs ^ (row & 7)) * 8),
            Ks + c * 8);
    }
#pragma unroll
    for (int i = 0; i < 4; i++) {
      const int c = i * 256 + tid, row = c >> 3, cs = c & 7;
      gll16(Vt + (size_t)(h * HD + row) * S_SEQ + kvb * 64 + ((cs ^ (row & 7)) * 8),
            Vs + c * 8);
    }
    __syncthreads();

    f32x16_t sA = {}, sB = {};
#pragma unroll
    for (int ds = 0; ds < 8; ds++) {
      const int ch = ((hi + ds * 2) ^ (lo & 7)) * 8;
      bf16x8 kA = *(const bf16x8*)(Ks + lo * 128 + ch);
      bf16x8 kB = *(const bf16x8*)(Ks + (32 + lo) * 128 + ch);
      sA = __builtin_amdgcn_mfma_f32_32x32x16_bf16(kA, qf[ds], sA, 0, 0, 0);
      sB = __builtin_amdgcn_mfma_f32_32x32x16_bf16(kB, qf[ds], sB, 0, 0, 0);
    }

    float p[32];
#pragma unroll
    for (int i = 0; i < 16; i++) { p[i] = sA[i]; p[16 + i] = sB[i]; }
    float pm = p[0];
#pragma unroll
    for (int i = 1; i < 32; i++) pm = fmaxf(pm, p[i]);
    pm = fmaxf(pm, __shfl_xor(pm, 32));
    const float mn = fmaxf(m_run, pm);
    const float corr = __expf(m_run - mn);
    m_run = mn;
    float ps = 0.f;
#pragma unroll
    for (int i = 0; i < 32; i++) { p[i] = __expf(p[i] - mn); ps += p[i]; }
    ps += __shfl_xor(ps, 32);
    l_run = l_run * corr + ps;
#pragma unroll
    for (int nt = 0; nt < 4; nt++) o[nt] *= corr;

    uint32_t c[16];
#pragma unroll
    for (int j = 0; j < 16; j++) c[j] = pk2(p[2 * j], p[2 * j + 1]);
    bf16x8 pf[4];
#pragma unroll
    for (int s = 0; s < 4; s++) {
      const uint32_t ca = c[4 * s], cb = c[4 * s + 1], cc = c[4 * s + 2], cd = c[4 * s + 3];
      const uint32_t sa = __shfl_xor(ca, 32), sb = __shfl_xor(cb, 32);
      const uint32_t sc = __shfl_xor(cc, 32), sd = __shfl_xor(cd, 32);
      union { uint32_t u[4]; bf16x8 v; } f;
      f.u[0] = hi ? sc : ca; f.u[1] = hi ? sd : cb;
      f.u[2] = hi ? cc : sa; f.u[3] = hi ? cd : sb;
      pf[s] = f.v;
    }

#pragma unroll
    for (int nt = 0; nt < 4; nt++) {
      const int vrow = nt * 32 + lo;
#pragma unroll
      for (int s = 0; s < 4; s++) {
        bf16x8 vf = *(const bf16x8*)(Vs + vrow * 64 + (((s * 2 + hi) ^ (lo & 7)) * 8));
        o[nt] = __builtin_amdgcn_mfma_f32_32x32x16_bf16(vf, pf[s], o[nt], 0, 0, 0);
      }
    }
  }

  const float inv = 1.0f / l_run;
#pragma unroll
  for (int nt = 0; nt < 4; nt++) o[nt] *= inv;

  __syncthreads();
  float* tb = (float*)smem + wid * (32 * 33);
  const int q2 = l >> 1, dh = (l & 1) * 16;
#pragma unroll
  for (int nt = 0; nt < 4; nt++) {
#pragma unroll
    for (int r = 0; r < 16; r++)
      tb[lo * 33 + ((r & 3) + 8 * (r >> 2) + 4 * hi)] = o[nt][r];
    asm volatile("s_waitcnt lgkmcnt(0)" ::: "memory");
    __builtin_amdgcn_sched_barrier(0);
    ushort tmp[16];
#pragma unroll
    for (int j = 0; j < 16; j++) tmp[j] = f2b(tb[q2 * 33 + dh + j]);
    asm volatile("s_waitcnt lgkmcnt(0)" ::: "memory");
    __builtin_amdgcn_sched_barrier(0);
    const size_t oaddr = (size_t)(q0 + q2) * DIM + h * HD + nt * 32 + dh;
    *(uint4*)(Ob + oaddr) = *(uint4*)tmp;
    *(uint4*)(Ob + oaddr + 8) = *(uint4*)(tmp + 8);
  }
}

extern "C" void kernel_launch(void* const* d_in, const int* in_sizes, int n_in,
                              void* d_out, int out_size, void* d_ws, size_t ws_size,
                              hipStream_t stream) {
  const float* x   = (const float*)d_in[0];
  const float* ctx = (const float*)d_in[1];
  const float* Wq  = (const float*)d_in[2];
  const float* bq  = (const float*)d_in[3];
  const float* Wk  = (const float*)d_in[4];
  const float* bk  = (const float*)d_in[5];
  const float* Wv  = (const float*)d_in[6];
  const float* bv  = (const float*)d_in[7];
  const float* Wo  = (const float*)d_in[8];
  const float* bo  = (const float*)d_in[9];
  const float* gq  = (const float*)d_in[10];
  const float* gk  = (const float*)d_in[11];

  char* ws = (char*)d_ws;
  ushort* wqt   = (ushort*)(ws);                 // [2048][2048] bf16   8.39MB
  ushort* wkt   = (ushort*)(ws + 8388608);       // [2048][4096] bf16  16.78MB  } adjacent =>
  ushort* wvt   = (ushort*)(ws + 25165824);      // [2048][4096] bf16  16.78MB  } [4096][4096] KV
  ushort* wot   = (ushort*)(ws + 41943040);      // [2048][2048] bf16   8.39MB
  ushort* qb    = (ushort*)(ws + 50331648);      // [8192][2048] bf16  33.55MB (normalized Q)
  ushort* kb    = (ushort*)(ws + 83886080);      // [512][2048]  bf16   2.10MB (normalized K)
  ushort* vt    = (ushort*)(ws + 85983232);      // [2048][512]  bf16   2.10MB (V^T per-head)
  ushort* xb    = (ushort*)(ws + 88080384);      // [8192][2048] bf16  33.55MB (x cast)
  ushort* ctxb  = (ushort*)(ws + 88080384);      // [512][4096]  bf16   4.19MB (reuses xb)
  ushort* qraw  = (ushort*)(ws + 121634816);     // [8192][2048] bf16  33.55MB (pre-norm Q)
  ushort* kraw  = (ushort*)(ws + 121634816);     // [512][2048]  bf16   2.10MB (reuses qraw)
  ushort* attnb = (ushort*)(ws + 121634816);     // [8192][2048] bf16  33.55MB (reuses after K norm)

  // input casts + weight transposes
  k_cast<<<L_SEQ * DIM / 8 / 256, 256, 0, stream>>>(x, xb);
  k_tcast<<<dim3(DIM / 32, DIM / 32), dim3(32, 8), 0, stream>>>(Wq, wqt, DIM, DIM);
  k_tcast<<<dim3(DIM / 32, CTX / 32), dim3(32, 8), 0, stream>>>(Wk, wkt, CTX, DIM);
  k_tcast<<<dim3(DIM / 32, CTX / 32), dim3(32, 8), 0, stream>>>(Wv, wvt, CTX, DIM);
  k_tcast<<<dim3(DIM / 32, DIM / 32), dim3(32, 8), 0, stream>>>(Wo, wot, DIM, DIM);

  // Q path: q_raw = x@Wq + bq (bf16) -> rmsnorm*g_q with softmax scale folded
  k_gemm256<1><<<dim3(DIM / 256, L_SEQ / 256), 512, 0, stream>>>(xb, wqt, bq, qraw, L_SEQ, DIM, DIM);
  k_cast<<<S_SEQ * CTX / 8 / 256, 256, 0, stream>>>(ctx, ctxb);
  k_rmsnorm<<<L_SEQ, 256, 0, stream>>>(qraw, qb, gq, 0.08838834764831843f);
  // fused K+V projection: Bt = [Wk^T ; Wv^T] (adjacent in ws), N=4096
  k_gemm_bt<3><<<dim3(2 * DIM / 128, S_SEQ / 128), 256, 0, stream>>>(ctxb, wkt, bk, bv, kraw, vt, S_SEQ, 2 * DIM, CTX);
  k_rmsnorm<<<S_SEQ, 256, 0, stream>>>(kraw, kb, gk, 1.0f);
  // attention (swapped-operand 32x32 structure)
  k_attn<<<L_SEQ / 128 * NH, 256, 0, stream>>>(qb, kb, vt, attnb);
  // out = attn @ Wo + bo (fp32)
  k_gemm256<0><<<dim3(DIM / 256, L_SEQ / 256), 512, 0, stream>>>(attnb, wot, bo, d_out, L_SEQ, DIM, DIM);
}

// Round 7
// 337.548 us; speedup vs baseline: 2.0723x; 1.0531x over previous
//
#include <hip/hip_runtime.h>
#include <hip/hip_bf16.h>
#include <stdint.h>

#define L_SEQ 8192
#define S_SEQ 512
#define DIM   2048
#define CTX   4096
#define NH    16
#define HD    128

typedef __bf16 bf16_t;
typedef bf16_t bf16x8 __attribute__((ext_vector_type(8)));
typedef float  f32x4_t __attribute__((ext_vector_type(4)));
typedef float  f32x16_t __attribute__((ext_vector_type(16)));

__device__ __forceinline__ ushort f2b(float f) {
  union { float f; uint32_t u; } v; v.f = f;
  uint32_t u = v.u;
  uint32_t r = (u + 0x7fffu + ((u >> 16) & 1u)) >> 16;
  return (ushort)r;
}
__device__ __forceinline__ uint32_t pk2(float a, float b) {
  return (uint32_t)f2b(a) | ((uint32_t)f2b(b) << 16);
}
__device__ __forceinline__ float b2f(ushort u) {
  union { uint32_t u; float f; } v; v.u = ((uint32_t)u) << 16;
  return v.f;
}
__device__ __forceinline__ void gll16(const ushort* g, ushort* l) {
  __builtin_amdgcn_global_load_lds((const __attribute__((address_space(1))) void*)g,
                                   (__attribute__((address_space(3))) void*)l, 16, 0, 0);
}

// ---------------- elementwise cast fp32 -> bf16 (8 elems/thread) ----------------
__global__ __launch_bounds__(256) void k_cast(const float* __restrict__ in,
                                              ushort* __restrict__ out) {
  const size_t i = ((size_t)blockIdx.x * 256 + threadIdx.x) * 8;
  float4 a = *(const float4*)(in + i);
  float4 b = *(const float4*)(in + i + 4);
  uint4 r;
  r.x = pk2(a.x, a.y); r.y = pk2(a.z, a.w);
  r.z = pk2(b.x, b.y); r.w = pk2(b.z, b.w);
  *(uint4*)(out + i) = r;
}

// ---------------- transpose + cast fp32 [K][N] -> bf16 [N][K] ----------------
__global__ __launch_bounds__(256) void k_tcast(const float* __restrict__ src,
                                               ushort* __restrict__ dst, int K, int N) {
  __shared__ float t[32][33];
  int tx = threadIdx.x, ty = threadIdx.y;
  int n0 = blockIdx.x * 32, k0 = blockIdx.y * 32;
#pragma unroll
  for (int i = 0; i < 4; i++)
    t[ty + 8 * i][tx] = src[(size_t)(k0 + ty + 8 * i) * N + n0 + tx];
  __syncthreads();
#pragma unroll
  for (int i = 0; i < 4; i++)
    dst[(size_t)(n0 + ty + 8 * i) * K + k0 + tx] = f2b(t[tx][ty + 8 * i]);
}

// ---------------- RMSNorm row kernel: bf16 [rows][2048] -> bf16, fused extra scale ----
__global__ __launch_bounds__(256) void k_rmsnorm(const ushort* __restrict__ in,
                                                 ushort* __restrict__ out,
                                                 const float* __restrict__ g, float scale) {
  const int row = blockIdx.x, tid = threadIdx.x;
  uint4 v = *(const uint4*)(in + (size_t)row * DIM + tid * 8);
  const uint32_t* vu = (const uint32_t*)&v;
  float f[8];
#pragma unroll
  for (int i = 0; i < 4; i++) {
    f[2 * i]     = b2f((ushort)(vu[i] & 0xffffu));
    f[2 * i + 1] = b2f((ushort)(vu[i] >> 16));
  }
  float s = 0.f;
#pragma unroll
  for (int i = 0; i < 8; i++) s += f[i] * f[i];
#pragma unroll
  for (int off = 32; off; off >>= 1) s += __shfl_down(s, off);
  __shared__ float wsum[4];
  __shared__ float rtot;
  if ((tid & 63) == 0) wsum[tid >> 6] = s;
  __syncthreads();
  if (tid == 0)
    rtot = rsqrtf((wsum[0] + wsum[1] + wsum[2] + wsum[3]) * (1.0f / DIM) + 1e-6f);
  __syncthreads();
  const float rms = rtot * scale;
  const float* gp = g + tid * 8;
  float4 g0 = *(const float4*)gp, g1 = *(const float4*)(gp + 4);
  ushort r[8];
  r[0] = f2b(f[0] * rms * g0.x); r[1] = f2b(f[1] * rms * g0.y);
  r[2] = f2b(f[2] * rms * g0.z); r[3] = f2b(f[3] * rms * g0.w);
  r[4] = f2b(f[4] * rms * g1.x); r[5] = f2b(f[5] * rms * g1.y);
  r[6] = f2b(f[6] * rms * g1.z); r[7] = f2b(f[7] * rms * g1.w);
  *(uint4*)(out + (size_t)row * DIM + tid * 8) = *(uint4*)r;
}

// ======================= 256x256 8-wave 4-phase GEMM =======================
template <int OUT_MODE>
__global__ __launch_bounds__(512, 2) void k_gemm256(const ushort* __restrict__ A,
                                                    const ushort* __restrict__ Bt,
                                                    const float* __restrict__ bias,
                                                    void* __restrict__ outp,
                                                    int M, int N, int K) {
  __shared__ __align__(16) ushort lds[65536];  // 128 KB
  const int tid = threadIdx.x;
  const int l = tid & 63, wid = tid >> 6;
  const int wm = wid >> 2, wn = wid & 3;
  const int lr = l & 15, lq = l >> 4;

  const int nwg = gridDim.x * gridDim.y;
  const int bid = blockIdx.y * gridDim.x + blockIdx.x;
  const int swz = (bid & 7) * (nwg >> 3) + (bid >> 3);
  const int m0 = (swz / gridDim.x) * 256, n0 = (swz % gridDim.x) * 256;

  f32x4_t acc[8][4];
#pragma unroll
  for (int i = 0; i < 8; i++)
#pragma unroll
    for (int j = 0; j < 4; j++) acc[i][j] = f32x4_t{0.f, 0.f, 0.f, 0.f};

  const int srow = l >> 3;
  const int schunk = ((l & 7) ^ (srow & 7)) * 8;
  auto stage = [&](int buf, int tile, int mat, int h) {
    const ushort* gp = mat ? Bt : A;
    const int rn0 = mat ? n0 : m0;
    const size_t r0 = (size_t)(rn0 + h * 128 + wid * 8 + srow);
    const ushort* g0 = gp + r0 * K + tile * 64 + schunk;
    ushort* l0 = &lds[buf * 32768 + mat * 16384 + (h * 128 + wid * 8) * 64];
    gll16(g0, l0);
    gll16(g0 + (size_t)64 * K, l0 + 64 * 64);
  };

  auto rdA = [&](int buf, int mf, int ks) -> bf16x8 {
    const int R = wm * 128 + mf * 16 + lr;
    return *(const bf16x8*)(&lds[buf * 32768 + R * 64 + (((ks * 4 + lq) ^ (R & 7)) * 8)]);
  };
  auto rdB = [&](int buf, int nf, int ks) -> bf16x8 {
    const int R = wn * 64 + nf * 16 + lr;
    return *(const bf16x8*)(&lds[buf * 32768 + 16384 + R * 64 + (((ks * 4 + lq) ^ (R & 7)) * 8)]);
  };

  const int NT = K >> 6;
  stage(0, 0, 0, 0); stage(0, 0, 0, 1); stage(0, 0, 1, 0); stage(0, 0, 1, 1);

  bf16x8 a[4][2], a2[4][2], b[2][2], b2[2][2];
  for (int kt = 0; kt < NT; kt++) {
    const int cur = kt & 1, nxt = cur ^ 1;
    const bool pf = (kt + 1 < NT);
    if (pf) { stage(nxt, kt + 1, 0, 0); asm volatile("s_waitcnt vmcnt(2)" ::: "memory"); }
    else    { asm volatile("s_waitcnt vmcnt(0)" ::: "memory"); }
    __builtin_amdgcn_sched_barrier(0);
    __builtin_amdgcn_s_barrier();
    __builtin_amdgcn_sched_barrier(0);
#pragma unroll
    for (int mf = 0; mf < 4; mf++) { a[mf][0] = rdA(cur, mf, 0); a[mf][1] = rdA(cur, mf, 1); }
#pragma unroll
    for (int nf = 0; nf < 2; nf++) { b[nf][0] = rdB(cur, nf, 0); b[nf][1] = rdB(cur, nf, 1); }
    __builtin_amdgcn_s_setprio(1);
#pragma unroll
    for (int mf = 0; mf < 4; mf++)
#pragma unroll
      for (int nf = 0; nf < 2; nf++) {
        acc[mf][nf] = __builtin_amdgcn_mfma_f32_16x16x32_bf16(a[mf][0], b[nf][0], acc[mf][nf], 0, 0, 0);
        acc[mf][nf] = __builtin_amdgcn_mfma_f32_16x16x32_bf16(a[mf][1], b[nf][1], acc[mf][nf], 0, 0, 0);
      }
    __builtin_amdgcn_s_setprio(0);
    __builtin_amdgcn_sched_barrier(0);
    __builtin_amdgcn_s_barrier();
    __builtin_amdgcn_sched_barrier(0);
#pragma unroll
    for (int mf = 0; mf < 4; mf++) { a2[mf][0] = rdA(cur, mf + 4, 0); a2[mf][1] = rdA(cur, mf + 4, 1); }
    if (pf) stage(nxt, kt + 1, 0, 1);
    __builtin_amdgcn_sched_barrier(0);
    __builtin_amdgcn_s_barrier();
    __builtin_amdgcn_sched_barrier(0);
    __builtin_amdgcn_s_setprio(1);
#pragma unroll
    for (int mf = 0; mf < 4; mf++)
#pragma unroll
      for (int nf = 0; nf < 2; nf++) {
        acc[mf + 4][nf] = __builtin_amdgcn_mfma_f32_16x16x32_bf16(a2[mf][0], b[nf][0], acc[mf + 4][nf], 0, 0, 0);
        acc[mf + 4][nf] = __builtin_amdgcn_mfma_f32_16x16x32_bf16(a2[mf][1], b[nf][1], acc[mf + 4][nf], 0, 0, 0);
      }
    __builtin_amdgcn_s_setprio(0);
    __builtin_amdgcn_sched_barrier(0);
    __builtin_amdgcn_s_barrier();
    __builtin_amdgcn_sched_barrier(0);
#pragma unroll
    for (int nf = 0; nf < 2; nf++) { b2[nf][0] = rdB(cur, nf + 2, 0); b2[nf][1] = rdB(cur, nf + 2, 1); }
    if (pf) stage(nxt, kt + 1, 1, 0);
    __builtin_amdgcn_sched_barrier(0);
    __builtin_amdgcn_s_barrier();
    __builtin_amdgcn_sched_barrier(0);
    __builtin_amdgcn_s_setprio(1);
#pragma unroll
    for (int mf = 0; mf < 4; mf++)
#pragma unroll
      for (int nf = 0; nf < 2; nf++) {
        acc[mf + 4][nf + 2] = __builtin_amdgcn_mfma_f32_16x16x32_bf16(a2[mf][0], b2[nf][0], acc[mf + 4][nf + 2], 0, 0, 0);
        acc[mf + 4][nf + 2] = __builtin_amdgcn_mfma_f32_16x16x32_bf16(a2[mf][1], b2[nf][1], acc[mf + 4][nf + 2], 0, 0, 0);
      }
    __builtin_amdgcn_s_setprio(0);
    __builtin_amdgcn_sched_barrier(0);
    __builtin_amdgcn_s_barrier();
    __builtin_amdgcn_sched_barrier(0);
#pragma unroll
    for (int mf = 0; mf < 4; mf++) { a[mf][0] = rdA(cur, mf, 0); a[mf][1] = rdA(cur, mf, 1); }
    if (pf) stage(nxt, kt + 1, 1, 1);
    __builtin_amdgcn_sched_barrier(0);
    __builtin_amdgcn_s_barrier();
    __builtin_amdgcn_sched_barrier(0);
    __builtin_amdgcn_s_setprio(1);
#pragma unroll
    for (int mf = 0; mf < 4; mf++)
#pragma unroll
      for (int nf = 0; nf < 2; nf++) {
        acc[mf][nf + 2] = __builtin_amdgcn_mfma_f32_16x16x32_bf16(a[mf][0], b2[nf][0], acc[mf][nf + 2], 0, 0, 0);
        acc[mf][nf + 2] = __builtin_amdgcn_mfma_f32_16x16x32_bf16(a[mf][1], b2[nf][1], acc[mf][nf + 2], 0, 0, 0);
      }
    __builtin_amdgcn_s_setprio(0);
    __builtin_amdgcn_sched_barrier(0);
    __builtin_amdgcn_s_barrier();
    __builtin_amdgcn_sched_barrier(0);
  }

#pragma unroll
  for (int nf = 0; nf < 4; nf++) {
    const int col = n0 + wn * 64 + nf * 16 + lr;
    const float bv = bias[col];
#pragma unroll
    for (int mf = 0; mf < 8; mf++) {
#pragma unroll
      for (int r = 0; r < 4; r++) {
        const int row = m0 + wm * 128 + mf * 16 + lq * 4 + r;
        const float v = acc[mf][nf][r] + bv;
        if constexpr (OUT_MODE == 0)
          ((float*)outp)[(size_t)row * N + col] = v;
        else
          ((ushort*)outp)[(size_t)row * N + col] = f2b(v);
      }
    }
  }
}

// ============ KV projection GEMM: M=512, N=4096, K=4096, depth-4 pipeline ============
// Tile 128x64 -> grid 256 (1 block/CU). 4 LDS buffers; steady-state vmcnt(9)
// (3 stages x 3 loads/wave in flight). XCD swizzle m-fastest so the 4 m-blocks
// sharing a B-panel land on the same XCD (B fetched once, L2-resident).
// Split epilogue: cols<DIM -> K bf16 [512][2048]; cols>=DIM -> V^T bf16 [2048][512].
__global__ __launch_bounds__(256) void k_gemmkv(const ushort* __restrict__ A,
                                                const ushort* __restrict__ Bt,
                                                const float* __restrict__ biasK,
                                                const float* __restrict__ biasV,
                                                ushort* __restrict__ outK,
                                                ushort* __restrict__ outVt) {
  __shared__ __align__(16) ushort As[4][128 * 32];  // 32 KB
  __shared__ __align__(16) ushort Bs[4][64 * 32];   // 16 KB
  const int tid = threadIdx.x;
  const int l = tid & 63, wid = tid >> 6;
  const int wr = wid >> 1, wc = wid & 1;
  const int lr = l & 15, lq = l >> 4;
  const int K = CTX, M = S_SEQ;

  const int bid = blockIdx.x;                 // grid = 256
  const int swz = (bid & 7) * 32 + (bid >> 3);
  const int n0 = (swz >> 2) * 64, m0 = (swz & 3) * 128;

  f32x4_t acc[4][2];
#pragma unroll
  for (int i = 0; i < 4; i++)
#pragma unroll
    for (int j = 0; j < 2; j++) acc[i][j] = f32x4_t{0.f, 0.f, 0.f, 0.f};

  // staging: lane l writes LDS chunk (row l>>2, chunk l&3); global source chunk
  // carries the inverse bank swizzle g = (l&3) ^ ((srow>>1)&3).
  const int srow = l >> 2;
  const int schunk = ((l & 3) ^ ((srow >> 1) & 3)) * 8;
  const ushort* gA = A  + (size_t)(m0 + srow) * K + schunk;
  const ushort* gB = Bt + (size_t)(n0 + wid * 16 + srow) * K + schunk;

  auto stage = [&](int buf, int kt) {
    const int ko = kt * 32;
    gll16(gA + (size_t)(wid * 16) * K + ko,      &As[buf][(wid * 16) * 32]);
    gll16(gA + (size_t)(64 + wid * 16) * K + ko, &As[buf][(64 + wid * 16) * 32]);
    gll16(gB + ko,                               &Bs[buf][(wid * 16) * 32]);
  };
  // reads: chunk = lq ^ ((row>>1)&3) -> 16 lanes spread over all 8 bank groups
  auto rdA = [&](int buf, int mi) -> bf16x8 {
    const int R = wr * 64 + mi * 16 + lr;
    return *(const bf16x8*)(&As[buf][R * 32 + ((lq ^ ((R >> 1) & 3)) * 8)]);
  };
  auto rdB = [&](int buf, int ni) -> bf16x8 {
    const int R = wc * 32 + ni * 16 + lr;
    return *(const bf16x8*)(&Bs[buf][R * 32 + ((lq ^ ((R >> 1) & 3)) * 8)]);
  };

  const int NT = K >> 5;  // 128
  stage(0, 0); stage(1, 1); stage(2, 2);
  for (int t = 0; t < NT; t++) {
    const int cur = t & 3;
    if (t + 3 < NT) { stage((t + 3) & 3, t + 3); asm volatile("s_waitcnt vmcnt(9)" ::: "memory"); }
    else if (t + 2 < NT) { asm volatile("s_waitcnt vmcnt(6)" ::: "memory"); }
    else if (t + 1 < NT) { asm volatile("s_waitcnt vmcnt(3)" ::: "memory"); }
    else                 { asm volatile("s_waitcnt vmcnt(0)" ::: "memory"); }
    __builtin_amdgcn_sched_barrier(0);
    __builtin_amdgcn_s_barrier();   // tile `cur` resident (every wave drained its own)
    __builtin_amdgcn_sched_barrier(0);

    bf16x8 af[4], bfr[2];
#pragma unroll
    for (int mi = 0; mi < 4; mi++) af[mi] = rdA(cur, mi);
#pragma unroll
    for (int ni = 0; ni < 2; ni++) bfr[ni] = rdB(cur, ni);
    __builtin_amdgcn_s_setprio(1);
#pragma unroll
    for (int mi = 0; mi < 4; mi++)
#pragma unroll
      for (int ni = 0; ni < 2; ni++)
        acc[mi][ni] = __builtin_amdgcn_mfma_f32_16x16x32_bf16(af[mi], bfr[ni], acc[mi][ni], 0, 0, 0);
    __builtin_amdgcn_s_setprio(0);
    __builtin_amdgcn_sched_barrier(0);
    __builtin_amdgcn_s_barrier();   // reads of `cur` done before it is restaged
    __builtin_amdgcn_sched_barrier(0);
  }

#pragma unroll
  for (int mi = 0; mi < 4; mi++) {
#pragma unroll
    for (int ni = 0; ni < 2; ni++) {
      const int col = n0 + wc * 32 + ni * 16 + lr;
      const float bv = (col < DIM) ? biasK[col] : biasV[col - DIM];
#pragma unroll
      for (int r = 0; r < 4; r++) {
        const int row = m0 + wr * 64 + mi * 16 + lq * 4 + r;
        const float v = acc[mi][ni][r] + bv;
        if (col < DIM) outK[(size_t)row * DIM + col] = f2b(v);
        else           outVt[(size_t)(col - DIM) * M + row] = f2b(v);  // V^T
      }
    }
  }
}

// ============ Flash attention, swapped-operand 32x32x16 structure ============
__global__ __launch_bounds__(256) void k_attn(const ushort* __restrict__ Qb,
                                              const ushort* __restrict__ Kb,
                                              const ushort* __restrict__ Vt,
                                              ushort* __restrict__ Ob) {
  __shared__ __align__(16) ushort smem[16384];  // 32KB: Ks [64][128] + Vs [128][64]
  ushort* Ks = smem;
  ushort* Vs = smem + 64 * 128;

  const int tid = threadIdx.x;
  const int l = tid & 63, wid = tid >> 6;
  const int lo = l & 31, hi = l >> 5;

  const int bid = blockIdx.x;                  // grid = 1024
  const int swz = (bid & 7) * 128 + (bid >> 3);
  const int h = swz >> 6;
  const int q0 = (swz & 63) * 128 + wid * 32;

  bf16x8 qf[8];
  {
    const ushort* qp = Qb + (size_t)(q0 + lo) * DIM + h * HD + hi * 8;
#pragma unroll
    for (int ds = 0; ds < 8; ds++) qf[ds] = *(const bf16x8*)(qp + ds * 16);
  }

  f32x16_t o[4] = {};          // O^T: lane q = lo, d = nt*32 + crow(r,hi)
  float m_run = -1e30f, l_run = 0.f;

  for (int kvb = 0; kvb < S_SEQ / 64; kvb++) {
    __syncthreads();
#pragma unroll
    for (int i = 0; i < 4; i++) {
      const int c = i * 256 + tid, row = c >> 4, cs = c & 15;
      gll16(Kb + (size_t)(kvb * 64 + row) * DIM + h * HD + ((cs ^ (row & 7)) * 8),
            Ks + c * 8);
    }
#pragma unroll
    for (int i = 0; i < 4; i++) {
      const int c = i * 256 + tid, row = c >> 3, cs = c & 7;
      gll16(Vt + (size_t)(h * HD + row) * S_SEQ + kvb * 64 + ((cs ^ (row & 7)) * 8),
            Vs + c * 8);
    }
    __syncthreads();

    f32x16_t sA = {}, sB = {};
#pragma unroll
    for (int ds = 0; ds < 8; ds++) {
      const int ch = ((hi + ds * 2) ^ (lo & 7)) * 8;
      bf16x8 kA = *(const bf16x8*)(Ks + lo * 128 + ch);
      bf16x8 kB = *(const bf16x8*)(Ks + (32 + lo) * 128 + ch);
      sA = __builtin_amdgcn_mfma_f32_32x32x16_bf16(kA, qf[ds], sA, 0, 0, 0);
      sB = __builtin_amdgcn_mfma_f32_32x32x16_bf16(kB, qf[ds], sB, 0, 0, 0);
    }

    float p[32];
#pragma unroll
    for (int i = 0; i < 16; i++) { p[i] = sA[i]; p[16 + i] = sB[i]; }
    float pm = p[0];
#pragma unroll
    for (int i = 1; i < 32; i++) pm = fmaxf(pm, p[i]);
    pm = fmaxf(pm, __shfl_xor(pm, 32));
    const float mn = fmaxf(m_run, pm);
    const float corr = __expf(m_run - mn);
    m_run = mn;
    float ps = 0.f;
#pragma unroll
    for (int i = 0; i < 32; i++) { p[i] = __expf(p[i] - mn); ps += p[i]; }
    ps += __shfl_xor(ps, 32);
    l_run = l_run * corr + ps;
#pragma unroll
    for (int nt = 0; nt < 4; nt++) o[nt] *= corr;

    uint32_t c[16];
#pragma unroll
    for (int j = 0; j < 16; j++) c[j] = pk2(p[2 * j], p[2 * j + 1]);
    bf16x8 pf[4];
#pragma unroll
    for (int s = 0; s < 4; s++) {
      const uint32_t ca = c[4 * s], cb = c[4 * s + 1], cc = c[4 * s + 2], cd = c[4 * s + 3];
      const uint32_t sa = __shfl_xor(ca, 32), sb = __shfl_xor(cb, 32);
      const uint32_t sc = __shfl_xor(cc, 32), sd = __shfl_xor(cd, 32);
      union { uint32_t u[4]; bf16x8 v; } f;
      f.u[0] = hi ? sc : ca; f.u[1] = hi ? sd : cb;
      f.u[2] = hi ? cc : sa; f.u[3] = hi ? cd : sb;
      pf[s] = f.v;
    }

#pragma unroll
    for (int nt = 0; nt < 4; nt++) {
      const int vrow = nt * 32 + lo;
#pragma unroll
      for (int s = 0; s < 4; s++) {
        bf16x8 vf = *(const bf16x8*)(Vs + vrow * 64 + (((s * 2 + hi) ^ (lo & 7)) * 8));
        o[nt] = __builtin_amdgcn_mfma_f32_32x32x16_bf16(vf, pf[s], o[nt], 0, 0, 0);
      }
    }
  }

  const float inv = 1.0f / l_run;
#pragma unroll
  for (int nt = 0; nt < 4; nt++) o[nt] *= inv;

  __syncthreads();
  float* tb = (float*)smem + wid * (32 * 33);
  const int q2 = l >> 1, dh = (l & 1) * 16;
#pragma unroll
  for (int nt = 0; nt < 4; nt++) {
#pragma unroll
    for (int r = 0; r < 16; r++)
      tb[lo * 33 + ((r & 3) + 8 * (r >> 2) + 4 * hi)] = o[nt][r];
    asm volatile("s_waitcnt lgkmcnt(0)" ::: "memory");
    __builtin_amdgcn_sched_barrier(0);
    ushort tmp[16];
#pragma unroll
    for (int j = 0; j < 16; j++) tmp[j] = f2b(tb[q2 * 33 + dh + j]);
    asm volatile("s_waitcnt lgkmcnt(0)" ::: "memory");
    __builtin_amdgcn_sched_barrier(0);
    const size_t oaddr = (size_t)(q0 + q2) * DIM + h * HD + nt * 32 + dh;
    *(uint4*)(Ob + oaddr) = *(uint4*)tmp;
    *(uint4*)(Ob + oaddr + 8) = *(uint4*)(tmp + 8);
  }
}

extern "C" void kernel_launch(void* const* d_in, const int* in_sizes, int n_in,
                              void* d_out, int out_size, void* d_ws, size_t ws_size,
                              hipStream_t stream) {
  const float* x   = (const float*)d_in[0];
  const float* ctx = (const float*)d_in[1];
  const float* Wq  = (const float*)d_in[2];
  const float* bq  = (const float*)d_in[3];
  const float* Wk  = (const float*)d_in[4];
  const float* bk  = (const float*)d_in[5];
  const float* Wv  = (const float*)d_in[6];
  const float* bv  = (const float*)d_in[7];
  const float* Wo  = (const float*)d_in[8];
  const float* bo  = (const float*)d_in[9];
  const float* gq  = (const float*)d_in[10];
  const float* gk  = (const float*)d_in[11];

  char* ws = (char*)d_ws;
  ushort* wqt   = (ushort*)(ws);                 // [2048][2048] bf16   8.39MB
  ushort* wkt   = (ushort*)(ws + 8388608);       // [2048][4096] bf16  16.78MB  } adjacent =>
  ushort* wvt   = (ushort*)(ws + 25165824);      // [2048][4096] bf16  16.78MB  } [4096][4096] KV
  ushort* wot   = (ushort*)(ws + 41943040);      // [2048][2048] bf16   8.39MB
  ushort* qb    = (ushort*)(ws + 50331648);      // [8192][2048] bf16  33.55MB (normalized Q)
  ushort* kb    = (ushort*)(ws + 83886080);      // [512][2048]  bf16   2.10MB (normalized K)
  ushort* vt    = (ushort*)(ws + 85983232);      // [2048][512]  bf16   2.10MB (V^T per-head)
  ushort* xb    = (ushort*)(ws + 88080384);      // [8192][2048] bf16  33.55MB (x cast)
  ushort* ctxb  = (ushort*)(ws + 88080384);      // [512][4096]  bf16   4.19MB (reuses xb)
  ushort* qraw  = (ushort*)(ws + 121634816);     // [8192][2048] bf16  33.55MB (pre-norm Q)
  ushort* kraw  = (ushort*)(ws + 121634816);     // [512][2048]  bf16   2.10MB (reuses qraw)
  ushort* attnb = (ushort*)(ws + 121634816);     // [8192][2048] bf16  33.55MB (reuses after K norm)

  // input casts + weight transposes
  k_cast<<<L_SEQ * DIM / 8 / 256, 256, 0, stream>>>(x, xb);
  k_tcast<<<dim3(DIM / 32, DIM / 32), dim3(32, 8), 0, stream>>>(Wq, wqt, DIM, DIM);
  k_tcast<<<dim3(DIM / 32, CTX / 32), dim3(32, 8), 0, stream>>>(Wk, wkt, CTX, DIM);
  k_tcast<<<dim3(DIM / 32, CTX / 32), dim3(32, 8), 0, stream>>>(Wv, wvt, CTX, DIM);
  k_tcast<<<dim3(DIM / 32, DIM / 32), dim3(32, 8), 0, stream>>>(Wo, wot, DIM, DIM);

  // Q path: q_raw = x@Wq + bq (bf16) -> rmsnorm*g_q with softmax scale folded
  k_gemm256<1><<<dim3(DIM / 256, L_SEQ / 256), 512, 0, stream>>>(xb, wqt, bq, qraw, L_SEQ, DIM, DIM);
  k_cast<<<S_SEQ * CTX / 8 / 256, 256, 0, stream>>>(ctx, ctxb);
  k_rmsnorm<<<L_SEQ, 256, 0, stream>>>(qraw, qb, gq, 0.08838834764831843f);
  // fused K+V projection: Bt = [Wk^T ; Wv^T] (adjacent in ws), N=4096
  k_gemmkv<<<256, 256, 0, stream>>>(ctxb, wkt, bk, bv, kraw, vt);
  k_rmsnorm<<<S_SEQ, 256, 0, stream>>>(kraw, kb, gk, 1.0f);
  // attention (swapped-operand 32x32 structure)
  k_attn<<<L_SEQ / 128 * NH, 256, 0, stream>>>(qb, kb, vt, attnb);
  // out = attn @ Wo + bo (fp32)
  k_gemm256<0><<<dim3(DIM / 256, L_SEQ / 256), 512, 0, stream>>>(attnb, wot, bo, d_out, L_SEQ, DIM, DIM);
}